// Round 11
// baseline (926.378 us; speedup 1.0000x reference)
//
#include <hip/hip_runtime.h>
#include <math.h>

typedef float f4 __attribute__((ext_vector_type(4)));
typedef short s8 __attribute__((ext_vector_type(8)));

#define WS_FLOATS 66000000L
__device__ float g_fallback[WS_FLOATS];

__device__ __forceinline__ f4 ldg4(const float* p) { return *(const f4*)p; }

__device__ __forceinline__ unsigned short bfr(float x) {   // fp32 -> bf16 RNE
    unsigned int u = __float_as_uint(x);
    u += 0x7fffu + ((u >> 16) & 1u);
    return (unsigned short)(u >> 16);
}
__device__ __forceinline__ float bff(unsigned short h) {
    return __uint_as_float(((unsigned int)h) << 16);
}
__device__ __forceinline__ s8 z8() { s8 z = {0,0,0,0,0,0,0,0}; return z; }

__device__ __forceinline__ void split8(const f4& x0, const f4& x1, s8& hi, s8& lo) {
#pragma unroll
    for (int e = 0; e < 4; ++e) {
        unsigned short h0 = bfr(x0[e]);
        hi[e] = (short)h0; lo[e] = (short)bfr(x0[e] - bff(h0));
        unsigned short h1 = bfr(x1[e]);
        hi[e + 4] = (short)h1; lo[e + 4] = (short)bfr(x1[e] - bff(h1));
    }
}

#define MFMA16(d, a, b) d = __builtin_amdgcn_mfma_f32_16x16x32_bf16(a, b, d, 0, 0, 0)

// ============================================================
// e2_gemm: E2 (h1 -> h2), bf16x2-split, 256x128 tile, BK=32 deep pipeline.
// 4-phase read-ahead interleave: each phase issues the NEXT phase's A-frag
// ds_reads, then waits (counted lgkm, in-order ds retirement) and runs 12
// MFMA -> read latency hides under MFMA. Sync skeleton unchanged from R10.
// ============================================================
__global__ __launch_bounds__(512, 2)
void e2_gemm(const short* __restrict__ aHi, const short* __restrict__ aLo,
             const short* __restrict__ wHi, const short* __restrict__ wLo,
             const float* __restrict__ bias, const float* __restrict__ gamma,
             const float* __restrict__ beta,
             short* __restrict__ oHi, short* __restrict__ oLo, float bns)
{
    extern __shared__ short smem[];
    const int tid = threadIdx.x;
    const int w = tid >> 6, l = tid & 63;
    const int fr = l & 15, fq = l >> 4;
    const int wm = (w >> 1) * 64;
    const int wn = (w & 1) * 64;

    int m0, n0;
    {
        const int nwg = gridDim.x;           // 784
        const int bid = blockIdx.x;
        const int q = nwg >> 3, r = nwg & 7;
        const int xcd = bid & 7, c = bid >> 3;
        const int wg = (xcd < r ? xcd * (q + 1) : r * (q + 1) + (xcd - r) * q) + c;
        m0 = (wg >> 2) * 256;
        n0 = (wg & 3) * 128;
    }

    const int lrow8 = l >> 3;
    const int u = (l & 7) ^ lrow8;
    const short* aPlane = (u & 4) ? aLo : aHi;
    const short* wPlane = (u & 4) ? wLo : wHi;
    const int srcC = (u & 3) << 3;

    int aBase[4];
#pragma unroll
    for (int i = 0; i < 4; ++i) {
        int row = w * 32 + i * 8 + lrow8;
        int m = m0 + row;
        int b = m / 196; int rem = m - b * 196;
        int oi = rem / 14, oj = rem - oi * 14;
        aBase[i] = ((b * 15 + oi) * 15 + oj) * 256 + srcC;
    }
    int bBase[2];
#pragma unroll
    for (int j = 0; j < 2; ++j) {
        int r2 = w * 16 + j * 8 + lrow8;
        bBase[j] = (n0 + r2) * 1024 + srcC;
    }

    auto stage = [&](int sel, int kc) {
        const int t = kc >> 8;
        const int toff = ((t >> 1) * 15 + (t & 1)) * 256 + (kc & 255);
        short* Ab = smem + sel * 16384;
        short* Bb = smem + 32768 + sel * 8192;
#pragma unroll
        for (int i = 0; i < 4; ++i)
            __builtin_amdgcn_global_load_lds(
                (const __attribute__((address_space(1))) void*)(aPlane + aBase[i] + toff),
                (__attribute__((address_space(3))) void*)(Ab + (w * 32 + i * 8) * 64),
                16, 0, 0);
#pragma unroll
        for (int j = 0; j < 2; ++j)
            __builtin_amdgcn_global_load_lds(
                (const __attribute__((address_space(1))) void*)(wPlane + bBase[j] + kc),
                (__attribute__((address_space(3))) void*)(Bb + (w * 16 + j * 8) * 64),
                16, 0, 0);
    };

    f4 acc[4][4];
#pragma unroll
    for (int a = 0; a < 4; ++a)
#pragma unroll
        for (int b = 0; b < 4; ++b) acc[a][b] = (f4){0.f, 0.f, 0.f, 0.f};

    stage(0, 0);
    stage(1, 32);

    for (int t = 0; t < 32; ++t) {
        const int sel = t & 1;
        if (t < 31) asm volatile("s_waitcnt vmcnt(6)" ::: "memory");
        else        asm volatile("s_waitcnt vmcnt(0)" ::: "memory");
        __builtin_amdgcn_s_barrier();
        __builtin_amdgcn_sched_barrier(0);

        const short* Ab = smem + sel * 16384;
        const short* Bb = smem + 32768 + sel * 8192;

        auto ardH = [&](int mf) {
            int ar = wm + mf * 16 + fr;
            return *(const s8*)&Ab[ar * 64 + (((fq) ^ (ar & 7)) << 3)];
        };
        auto ardL = [&](int mf) {
            int ar = wm + mf * 16 + fr;
            return *(const s8*)&Ab[ar * 64 + (((4 + fq) ^ (ar & 7)) << 3)];
        };

        s8 bfh[4], bfl[4];
#pragma unroll
        for (int nf = 0; nf < 4; ++nf) {
            int br = wn + nf * 16 + fr;
            bfh[nf] = *(const s8*)&Bb[br * 64 + ((fq ^ (br & 7)) << 3)];
        }
#pragma unroll
        for (int nf = 0; nf < 4; ++nf) {
            int br = wn + nf * 16 + fr;
            bfl[nf] = *(const s8*)&Bb[br * 64 + (((4 + fq) ^ (br & 7)) << 3)];
        }
        s8 aAh = ardH(0), aAl = ardL(0);

        // P0 (mf=0)
        asm volatile("s_waitcnt lgkmcnt(0)" ::: "memory");
        __builtin_amdgcn_sched_barrier(0);
        s8 aBh = ardH(1), aBl = ardL(1);
        __builtin_amdgcn_s_setprio(1);
#pragma unroll
        for (int nf = 0; nf < 4; ++nf) {
            MFMA16(acc[0][nf], aAh, bfh[nf]);
            MFMA16(acc[0][nf], aAh, bfl[nf]);
            MFMA16(acc[0][nf], aAl, bfh[nf]);
        }
        __builtin_amdgcn_s_setprio(0);
        // P1 (mf=1)
        aAh = ardH(2); aAl = ardL(2);
        asm volatile("s_waitcnt lgkmcnt(2)" ::: "memory");
        __builtin_amdgcn_sched_barrier(0);
        __builtin_amdgcn_s_setprio(1);
#pragma unroll
        for (int nf = 0; nf < 4; ++nf) {
            MFMA16(acc[1][nf], aBh, bfh[nf]);
            MFMA16(acc[1][nf], aBh, bfl[nf]);
            MFMA16(acc[1][nf], aBl, bfh[nf]);
        }
        __builtin_amdgcn_s_setprio(0);
        // P2 (mf=2)
        aBh = ardH(3); aBl = ardL(3);
        asm volatile("s_waitcnt lgkmcnt(2)" ::: "memory");
        __builtin_amdgcn_sched_barrier(0);
        __builtin_amdgcn_s_setprio(1);
#pragma unroll
        for (int nf = 0; nf < 4; ++nf) {
            MFMA16(acc[2][nf], aAh, bfh[nf]);
            MFMA16(acc[2][nf], aAh, bfl[nf]);
            MFMA16(acc[2][nf], aAl, bfh[nf]);
        }
        __builtin_amdgcn_s_setprio(0);
        // P3 (mf=3)
        asm volatile("s_waitcnt lgkmcnt(0)" ::: "memory");
        __builtin_amdgcn_sched_barrier(0);
        __builtin_amdgcn_s_setprio(1);
#pragma unroll
        for (int nf = 0; nf < 4; ++nf) {
            MFMA16(acc[3][nf], aBh, bfh[nf]);
            MFMA16(acc[3][nf], aBh, bfl[nf]);
            MFMA16(acc[3][nf], aBl, bfh[nf]);
        }
        __builtin_amdgcn_s_setprio(0);

        __builtin_amdgcn_s_barrier();              // all reads done; buf[sel] free
        __builtin_amdgcn_sched_barrier(0);
        if (t + 2 < 32) stage(sel, (t + 2) * 32);
    }

    // ---- epilogue: bn-relu, bf16 hi/lo pair ----
    float bi2[4], ga[4], be[4];
#pragma unroll
    for (int nf = 0; nf < 4; ++nf) {
        int col = n0 + wn + nf * 16 + fr;
        bi2[nf] = bias[col]; ga[nf] = gamma[col]; be[nf] = beta[col];
    }
#pragma unroll
    for (int mf = 0; mf < 4; ++mf)
#pragma unroll
        for (int j = 0; j < 4; ++j) {
            long gm = m0 + wm + mf * 16 + fq * 4 + j;
#pragma unroll
            for (int nf = 0; nf < 4; ++nf) {
                float v = ga[nf] * ((acc[mf][nf][j] + bi2[nf]) * bns) + be[nf];
                v = fmaxf(v, 0.f);
                long o = gm * 512 + n0 + wn + nf * 16 + fr;
                unsigned short h = bfr(v);
                oHi[o] = (short)h;
                oLo[o] = (short)bfr(v - bff(h));
            }
        }
}

// ============================================================
// gemm256: 256x256-tile 8-wave plain-bf16 implicit-GEMM conv.
// 4-phase read-ahead interleave (m201-style): pre-issue B(ks0,ks1)+A(h0,ks0);
// each phase issues the next A quad, counted-lgkm waits, 16 MFMA.
// vmcnt/barrier/stage skeleton unchanged.
// ============================================================
template<int EPI>
__global__ __launch_bounds__(512, 2)
void gemm256(const short* __restrict__ aSrc, const short* __restrict__ wHi,
             const float* __restrict__ bias, const float* __restrict__ gamma,
             const float* __restrict__ beta, void* __restrict__ oHi,
             double* __restrict__ sacc, const short* __restrict__ zsrc,
             int IH, int IW, int OHOW, int OW, int N, int K, int off,
             int ntShift, float bns)
{
    extern __shared__ short smem[];

    const int tid = threadIdx.x;
    const int w = tid >> 6;
    const int l = tid & 63;
    const int lr = l >> 3;
    const int lc = l & 7;
    const int fr = l & 15, fq = l >> 4;
    const int wm = (w >> 2) * 128;
    const int wn = (w & 3) * 64;

    int m0, n0;
    {
        const int nwg = gridDim.x;
        const int bid = blockIdx.x;
        const int q = nwg >> 3, r = nwg & 7;
        const int xcd = bid & 7, c = bid >> 3;
        const int wg = (xcd < r ? xcd * (q + 1) : r * (q + 1) + (xcd - r) * q) + c;
        const int NTm1 = (1 << ntShift) - 1;
        m0 = (wg >> ntShift) * 256;
        n0 = (wg & NTm1) * 256;
    }

    int bOff[4], oiA[4], ojA[4], bRowB[4];
#pragma unroll
    for (int i = 0; i < 4; ++i) {
        int row = (w << 5) + (i << 3) + lr;
        int m = m0 + row;
        int b = m / OHOW; int rem = m - b * OHOW;
        oiA[i] = rem / OW; ojA[i] = rem - oiA[i] * OW;
        bOff[i] = b * IH * IW;
        bRowB[i] = (n0 + row) * K;
    }
    const int swz = (lc ^ lr) << 3;

    auto stage = [&](int sel, int kc) {
        short* Ab = smem + sel * 16384;
        short* Bb = smem + 32768 + sel * 16384;
        const int t = kc >> 9;
        const int ci = (kc & 511) + swz;
        const int di = (t >> 1) + off, dj = (t & 1) + off;
#pragma unroll
        for (int i = 0; i < 4; ++i) {
            int ii = oiA[i] + di, jj = ojA[i] + dj;
            bool v = (ii >= 0) && (ii < IH) && (jj >= 0) && (jj < IW);
            const short* sA = v ? aSrc + (long)(bOff[i] + ii * IW + jj) * 512 + ci
                                : zsrc + (l << 3);
            __builtin_amdgcn_global_load_lds(
                (const __attribute__((address_space(1))) void*)sA,
                (__attribute__((address_space(3))) void*)(Ab + (((w << 5) + (i << 3)) * 64)),
                16, 0, 0);
            const short* sB = wHi + bRowB[i] + kc + swz;
            __builtin_amdgcn_global_load_lds(
                (const __attribute__((address_space(1))) void*)sB,
                (__attribute__((address_space(3))) void*)(Bb + (((w << 5) + (i << 3)) * 64)),
                16, 0, 0);
        }
    };

    f4 acc[8][4];
#pragma unroll
    for (int a = 0; a < 8; ++a)
#pragma unroll
        for (int b = 0; b < 4; ++b) acc[a][b] = (f4){0.f, 0.f, 0.f, 0.f};

    const int NT = K >> 6;
    stage(0, 0);
    stage(1, 64);

    for (int t = 0; t < NT; ++t) {
        const int sel = t & 1;
        const short* Ab = smem + sel * 16384;
        const short* Bb = smem + 32768 + sel * 16384;

        if (t < NT - 1) asm volatile("s_waitcnt vmcnt(8)" ::: "memory");
        else            asm volatile("s_waitcnt vmcnt(0)" ::: "memory");
        __builtin_amdgcn_s_barrier();
        __builtin_amdgcn_sched_barrier(0);

        auto ard = [&](int mf, int ks) {
            int row = wm + mf * 16 + fr;
            return *(const s8*)&Ab[row * 64 + (((ks * 4 + fq) ^ (row & 7)) << 3)];
        };

        s8 bf0[4], bf1[4], afA[4], afB[4];
#pragma unroll
        for (int nf = 0; nf < 4; ++nf) {
            int row = wn + nf * 16 + fr;
            bf0[nf] = *(const s8*)&Bb[row * 64 + ((fq ^ (row & 7)) << 3)];
        }
#pragma unroll
        for (int nf = 0; nf < 4; ++nf) {
            int row = wn + nf * 16 + fr;
            bf1[nf] = *(const s8*)&Bb[row * 64 + (((4 + fq) ^ (row & 7)) << 3)];
        }
#pragma unroll
        for (int mf = 0; mf < 4; ++mf) afA[mf] = ard(mf, 0);

        // P0: acc[0..3] x ks0
        asm volatile("s_waitcnt lgkmcnt(0)" ::: "memory");
        __builtin_amdgcn_sched_barrier(0);
#pragma unroll
        for (int mf = 0; mf < 4; ++mf) afB[mf] = ard(4 + mf, 0);
        __builtin_amdgcn_s_setprio(1);
#pragma unroll
        for (int mf = 0; mf < 4; ++mf)
#pragma unroll
            for (int nf = 0; nf < 4; ++nf) MFMA16(acc[mf][nf], afA[mf], bf0[nf]);
        __builtin_amdgcn_s_setprio(0);
        // P1: acc[4..7] x ks0
#pragma unroll
        for (int mf = 0; mf < 4; ++mf) afA[mf] = ard(mf, 1);
        asm volatile("s_waitcnt lgkmcnt(4)" ::: "memory");
        __builtin_amdgcn_sched_barrier(0);
        __builtin_amdgcn_s_setprio(1);
#pragma unroll
        for (int mf = 0; mf < 4; ++mf)
#pragma unroll
            for (int nf = 0; nf < 4; ++nf) MFMA16(acc[4 + mf][nf], afB[mf], bf0[nf]);
        __builtin_amdgcn_s_setprio(0);
        // P2: acc[0..3] x ks1
#pragma unroll
        for (int mf = 0; mf < 4; ++mf) afB[mf] = ard(4 + mf, 1);
        asm volatile("s_waitcnt lgkmcnt(4)" ::: "memory");
        __builtin_amdgcn_sched_barrier(0);
        __builtin_amdgcn_s_setprio(1);
#pragma unroll
        for (int mf = 0; mf < 4; ++mf)
#pragma unroll
            for (int nf = 0; nf < 4; ++nf) MFMA16(acc[mf][nf], afA[mf], bf1[nf]);
        __builtin_amdgcn_s_setprio(0);
        // P3: acc[4..7] x ks1
        asm volatile("s_waitcnt lgkmcnt(0)" ::: "memory");
        __builtin_amdgcn_sched_barrier(0);
        __builtin_amdgcn_s_setprio(1);
#pragma unroll
        for (int mf = 0; mf < 4; ++mf)
#pragma unroll
            for (int nf = 0; nf < 4; ++nf) MFMA16(acc[4 + mf][nf], afB[mf], bf1[nf]);
        __builtin_amdgcn_s_setprio(0);

        __builtin_amdgcn_s_barrier();              // all reads done; buf[sel] free
        __builtin_amdgcn_sched_barrier(0);
        if (t + 2 < NT) stage(sel, (t + 2) << 6);
    }

    if (EPI == 3) {
        float bi[4];
#pragma unroll
        for (int nf = 0; nf < 4; ++nf) bi[nf] = bias[n0 + wn + nf * 16 + fr];
        double tsum = 0.0;
#pragma unroll
        for (int mf = 0; mf < 8; ++mf)
#pragma unroll
            for (int j = 0; j < 4; ++j) {
                long gm = m0 + wm + mf * 16 + fq * 4 + j;
                float* orow = (float*)oHi + gm * (long)N + n0;
#pragma unroll
                for (int nf = 0; nf < 4; ++nf) {
                    float v = acc[mf][nf][j] + bi[nf];
                    orow[wn + nf * 16 + fr] = v;
                    tsum += (double)v * v;
                }
            }
        __syncthreads();
        double* rd = (double*)smem;
        rd[tid] = tsum; __syncthreads();
        for (int h = 256; h; h >>= 1) {
            if (tid < h) rd[tid] += rd[tid + h];
            __syncthreads();
        }
        if (tid == 0) atomicAdd(sacc, rd[0]);
    } else {
        float bi[4], ga[4], be[4];
#pragma unroll
        for (int nf = 0; nf < 4; ++nf) {
            int col = n0 + wn + nf * 16 + fr;
            bi[nf] = bias[col]; ga[nf] = gamma[col]; be[nf] = beta[col];
        }
#pragma unroll
        for (int mf = 0; mf < 8; ++mf)
#pragma unroll
            for (int j = 0; j < 4; ++j) {
                long gm = m0 + wm + mf * 16 + fq * 4 + j;
                short* orow = (short*)oHi + gm * (long)N + n0;
#pragma unroll
                for (int nf = 0; nf < 4; ++nf) {
                    float v = ga[nf] * ((acc[mf][nf][j] + bi[nf]) * bns) + be[nf];
                    orow[wn + nf * 16 + fr] = (short)bfr(fmaxf(v, 0.f));
                }
            }
    }
}

// ============================================================
// 128^2 template (proven) for split kernels, folds, VQ, and D3.
// ============================================================
template<int SPLIT, int ASRC, int EPI, int OUTF>
__global__ __launch_bounds__(256, 2)
void mfma_conv(const void* __restrict__ aHi, const void* __restrict__ aLo,
               const short* __restrict__ wHi, const short* __restrict__ wLo,
               const float* __restrict__ bias, const float* __restrict__ gamma,
               const float* __restrict__ beta,
               void* __restrict__ oHi, void* __restrict__ oLo,
               int* __restrict__ idxo,
               const float* __restrict__ xref, float* __restrict__ colsum,
               double* __restrict__ sacc,
               int IH, int IW, int Cin, int cinShift, int OHOW, int OW,
               int N, int K, int off, int ntShift, float bns)
{
    constexpr int PL = 128 * 64;
    constexpr int NPL = (SPLIT == 1) ? 3 : 4;
    __shared__ short smem[NPL * PL];
    short* Ah = smem;
    short* Al  = smem + PL;
    short* BhS = smem + 2 * PL;
    short* BlS = smem + 3 * PL;

    const int tid = threadIdx.x;
    const int lane = tid & 63, wid = tid >> 6;
    const int fr = lane & 15, fq = lane >> 4;
    const int wm = (wid >> 1) * 64, wn = (wid & 1) * 64;

    int m0, n0;
    {
        const int nwg = gridDim.x;
        const int bid = blockIdx.x;
        const int q = nwg >> 3, r = nwg & 7;
        const int xcd = bid & 7, c = bid >> 3;
        const int wg = (xcd < r ? xcd * (q + 1) : r * (q + 1) + (xcd - r) * q) + c;
        const int NTm1 = (1 << ntShift) - 1;
        m0 = (wg >> ntShift) * 128;
        n0 = (wg & NTm1) * 128;
    }

    const int sr = tid >> 1;
    const int skh = (tid & 1) << 5;

    long tapOff[4]; bool tv[4];
    {
        int m = m0 + sr;
        int b = m / OHOW; int rem = m - b * OHOW;
        int oi = rem / OW; int oj = rem - oi * OW;
#pragma unroll
        for (int t = 0; t < 4; ++t) {
            int ii = oi + (t >> 1) + off, jj = oj + (t & 1) + off;
            bool v = (ii >= 0) && (ii < IH) && (jj >= 0) && (jj < IW);
            tv[t] = v;
            tapOff[t] = ((long)b * IH + (v ? ii : 0)) * IW + (v ? jj : 0);
        }
    }

    f4 acc[4][4];
#pragma unroll
    for (int a = 0; a < 4; ++a)
#pragma unroll
        for (int b = 0; b < 4; ++b) acc[a][b] = (f4){0.f, 0.f, 0.f, 0.f};

    const short* wHrow = wHi + (long)(n0 + sr) * K;
    const short* wLrow = (SPLIT == 2) ? (wLo + (long)(n0 + sr) * K) : nullptr;

    const int swzW = (sr & 7) << 3;
    const int sbase = sr * 64;

    s8 rah[4], ral[4], rbh[4], rbl[4];
    f4 rax0[4], rax1[4];

    auto LOADREGS = [&](int kc) {
        const int kk = kc + skh;
        const int t = kk >> cinShift;
        const int ci = kk & (Cin - 1);
        const bool v = tv[t];
        if (ASRC == 0) {
            const float* p = (const float*)aHi + tapOff[t] * Cin + ci;
#pragma unroll
            for (int q = 0; q < 4; ++q) {
                rax0[q] = v ? ldg4(p + 8 * q) : (f4){0.f,0.f,0.f,0.f};
                rax1[q] = v ? ldg4(p + 8 * q + 4) : (f4){0.f,0.f,0.f,0.f};
            }
        } else if (ASRC == 1) {
            const short* ph = (const short*)aHi + tapOff[t] * Cin + ci;
            const short* pl = (const short*)aLo + tapOff[t] * Cin + ci;
#pragma unroll
            for (int q = 0; q < 4; ++q) {
                rah[q] = v ? *(const s8*)(ph + 8 * q) : z8();
                ral[q] = v ? *(const s8*)(pl + 8 * q) : z8();
            }
        } else {
            const short* ph = (const short*)aHi + tapOff[t] * Cin + ci;
#pragma unroll
            for (int q = 0; q < 4; ++q) rah[q] = v ? *(const s8*)(ph + 8 * q) : z8();
        }
        if (SPLIT == 2) {
#pragma unroll
            for (int q = 0; q < 4; ++q) {
                rbh[q] = *(const s8*)(wHrow + kc + skh + 8 * q);
                rbl[q] = *(const s8*)(wLrow + kc + skh + 8 * q);
            }
        }
    };

    auto STORE = [&]() {
        if (ASRC == 0) {
#pragma unroll
            for (int q = 0; q < 4; ++q) split8(rax0[q], rax1[q], rah[q], ral[q]);
        }
#pragma unroll
        for (int q = 0; q < 4; ++q) {
            int kx = (skh + 8 * q) ^ swzW;
            *(s8*)&Ah[sbase + kx] = rah[q];
            if (SPLIT == 2) {
                *(s8*)&Al[sbase + kx]  = ral[q];
                *(s8*)&BhS[sbase + kx] = rbh[q];
                *(s8*)&BlS[sbase + kx] = rbl[q];
            }
        }
    };

    auto stageB = [&](int bsel, int kc2) {
        short* bb = smem + (1 + bsel) * PL;
        const int rr0 = wid << 5;
#pragma unroll
        for (int i = 0; i < 4; ++i) {
            const int r = rr0 + 8 * i + (lane >> 3);
            const int c = lane & 7;
            const short* src = wHi + (long)(n0 + r) * K + kc2 + 8 * (c ^ (r & 7));
            __builtin_amdgcn_global_load_lds(
                (const __attribute__((address_space(1))) void*)src,
                (__attribute__((address_space(3))) void*)(bb + (rr0 + 8 * i) * 64),
                16, 0, 0);
        }
    };

    int bcur = 0;
    LOADREGS(0);
    if (SPLIT == 1) stageB(0, 0);

    for (int kc = 0; kc < K; kc += 64) {
        if (SPLIT == 1) {
            asm volatile("s_waitcnt lgkmcnt(0)" ::: "memory");
            __builtin_amdgcn_s_barrier();
            STORE();
            if (kc + 64 < K) {
                stageB(bcur ^ 1, kc + 64);
                asm volatile("s_waitcnt vmcnt(4)" ::: "memory");
            } else {
                asm volatile("s_waitcnt vmcnt(0)" ::: "memory");
            }
            __builtin_amdgcn_sched_barrier(0);
            asm volatile("s_waitcnt lgkmcnt(0)" ::: "memory");
            __builtin_amdgcn_s_barrier();
        } else {
            __syncthreads();
            STORE();
            __syncthreads();
        }
        if (kc + 64 < K) LOADREGS(kc + 64);

        const short* Bc = (SPLIT == 1) ? (smem + (1 + bcur) * PL) : BhS;

        __builtin_amdgcn_s_setprio(1);
#pragma unroll
        for (int ks = 0; ks < 2; ++ks) {
            const int colk = ks * 32 + fq * 8;
            s8 afh[4], afl[4], bfh[4], bfl[4];
#pragma unroll
            for (int mf = 0; mf < 4; ++mf) {
                int ar = wm + mf * 16 + fr;
                int ai = ar * 64 + (colk ^ ((ar & 7) << 3));
                afh[mf] = *(const s8*)&Ah[ai];
                if (SPLIT == 2) afl[mf] = *(const s8*)&Al[ai];
            }
#pragma unroll
            for (int nf = 0; nf < 4; ++nf) {
                int br = wn + nf * 16 + fr;
                int bi2 = br * 64 + (colk ^ ((br & 7) << 3));
                bfh[nf] = *(const s8*)&Bc[bi2];
                if (SPLIT == 2) bfl[nf] = *(const s8*)&BlS[bi2];
            }
#pragma unroll
            for (int mf = 0; mf < 4; ++mf)
#pragma unroll
                for (int nf = 0; nf < 4; ++nf) {
                    acc[mf][nf] = __builtin_amdgcn_mfma_f32_16x16x32_bf16(
                        afh[mf], bfh[nf], acc[mf][nf], 0, 0, 0);
                    if (SPLIT == 2) {
                        acc[mf][nf] = __builtin_amdgcn_mfma_f32_16x16x32_bf16(
                            afh[mf], bfl[nf], acc[mf][nf], 0, 0, 0);
                        acc[mf][nf] = __builtin_amdgcn_mfma_f32_16x16x32_bf16(
                            afl[mf], bfh[nf], acc[mf][nf], 0, 0, 0);
                    }
                }
        }
        __builtin_amdgcn_s_setprio(0);
        bcur ^= 1;
    }

    if (EPI == 2) {
        __syncthreads();
        float* pbv = (float*)smem;
        int*   piv = (int*)((float*)smem + 256);
        float cnv[4];
#pragma unroll
        for (int nf = 0; nf < 4; ++nf) cnv[nf] = bias[n0 + wn + nf * 16 + fr];
#pragma unroll
        for (int mf = 0; mf < 4; ++mf)
#pragma unroll
            for (int j = 0; j < 4; ++j) {
                float best = 3.4e38f; int bi = 0;
#pragma unroll
                for (int nf = 0; nf < 4; ++nf) {
                    float d = cnv[nf] - 2.0f * acc[mf][nf][j];
                    int col = wn + nf * 16 + fr;
                    if (d < best) { best = d; bi = col; }
                }
#pragma unroll
                for (int sh = 1; sh <= 8; sh <<= 1) {
                    float ov = __shfl_xor(best, sh, 64);
                    int ob = __shfl_xor(bi, sh, 64);
                    if (ov < best || (ov == best && ob < bi)) { best = ov; bi = ob; }
                }
                if (fr == 0) {
                    int r = wm + mf * 16 + fq * 4 + j;
                    pbv[(wid & 1) * 128 + r] = best;
                    piv[(wid & 1) * 128 + r] = bi;
                }
            }
        __syncthreads();
        double win = 0.0;
        if (tid < 128) {
            float b0 = pbv[tid], b1 = pbv[128 + tid];
            int i0 = piv[tid], i1 = piv[128 + tid];
            idxo[m0 + tid] = (b1 < b0) ? i1 : i0;
            win = (double)((b1 < b0) ? b1 : b0);
        }
        __syncthreads();
        double* rd = (double*)smem;
        rd[tid] = win; __syncthreads();
        for (int h = 128; h; h >>= 1) {
            if (tid < h) rd[tid] += rd[tid + h];
            __syncthreads();
        }
        if (tid == 0) atomicAdd(sacc, rd[0]);
        return;
    }

    float bi[4], ga[4], be[4];
#pragma unroll
    for (int nf = 0; nf < 4; ++nf) {
        int col = n0 + wn + nf * 16 + fr;
        bi[nf] = bias[col];
        if (EPI == 1) { ga[nf] = gamma[col]; be[nf] = beta[col]; }
    }
    double tsum = 0.0;
    float csum[4] = {0.f, 0.f, 0.f, 0.f};
#pragma unroll
    for (int mf = 0; mf < 4; ++mf)
#pragma unroll
        for (int j = 0; j < 4; ++j) {
            long gm = m0 + wm + mf * 16 + fq * 4 + j;
#pragma unroll
            for (int nf = 0; nf < 4; ++nf) {
                int col = n0 + wn + nf * 16 + fr;
                float vv = acc[mf][nf][j] + bi[nf];
                if (EPI == 1) {
                    vv = ga[nf] * (vv * bns) + be[nf];
                    vv = fmaxf(vv, 0.f);
                }
                long o = gm * (long)N + col;
                if (OUTF == 0) {
                    ((float*)oHi)[o] = vv;
                } else if (OUTF == 2) {
                    ((short*)oHi)[o] = (short)bfr(vv);
                } else {
                    unsigned short h = bfr(vv);
                    ((short*)oHi)[o] = (short)h;
                    ((short*)oLo)[o] = (short)bfr(vv - bff(h));
                }
                if (EPI == 3) tsum += (double)vv * vv;
                if (EPI == 4) {
                    float d = vv - xref[o];
                    tsum += (double)d * d;
                    csum[nf] += vv;
                }
            }
        }
    if (EPI == 4) {
        int bb128 = (m0 >> 8) * 128;
#pragma unroll
        for (int nf = 0; nf < 4; ++nf)
            atomicAdd(&colsum[bb128 + n0 + wn + nf * 16 + fr], csum[nf]);
    }
    if (EPI == 3 || EPI == 4) {
        __syncthreads();
        double* rd = (double*)smem;
        rd[tid] = tsum; __syncthreads();
        for (int h = 128; h; h >>= 1) {
            if (tid < h) rd[tid] += rd[tid + h];
            __syncthreads();
        }
        if (tid == 0) atomicAdd(sacc, rd[0]);
    }
}

// ---- single merged prep ----
__global__ void prep_all(const float* __restrict__ ew1, const float* __restrict__ ew2,
                         const float* __restrict__ ew3, const float* __restrict__ dw1,
                         const float* __restrict__ dw2, const float* __restrict__ dw3,
                         const float* __restrict__ cb,
                         short* __restrict__ ewt1h, short* __restrict__ ewt1l,
                         short* __restrict__ ewt2h, short* __restrict__ ewt2l,
                         short* __restrict__ ewt3h,
                         short* __restrict__ dwt1Th, short* __restrict__ dwt1Tl,
                         short* __restrict__ dwt2h, short* __restrict__ dwt3h,
                         short* __restrict__ cbh, short* __restrict__ cbl,
                         float* __restrict__ zbuf)
{
    int b = blockIdx.x;
    int t = threadIdx.x;
    if (b < 512) {
        int i = b * 256 + t; int n = i >> 9, k = i & 511;
        float x = ew1[(long)k * 256 + n]; unsigned short h = bfr(x);
        ewt1h[i] = (short)h; ewt1l[i] = (short)bfr(x - bff(h));
    } else if (b < 2560) {
        int i = (b - 512) * 256 + t; int n = i >> 10, k = i & 1023;
        float x = ew2[(long)k * 512 + n]; unsigned short h = bfr(x);
        ewt2h[i] = (short)h; ewt2l[i] = (short)bfr(x - bff(h));
    } else if (b < 10752) {
        int i = (b - 2560) * 256 + t; int n = i >> 11, k = i & 2047;
        ewt3h[i] = (short)bfr(ew3[(long)k * 1024 + n]);
    } else if (b < 18944) {
        int i = (b - 10752) * 256 + t; int Np = i >> 10, co = i & 1023;
        int tt = Np >> 9, nn = Np & 511;
        float x = dw1[((long)(tt * 1024 + co)) * 512 + nn]; unsigned short h = bfr(x);
        dwt1Th[i] = (short)h; dwt1Tl[i] = (short)bfr(x - bff(h));
    } else if (b < 20992) {
        int i = (b - 18944) * 256 + t; int n = i >> 11, k = i & 2047;
        dwt2h[i] = (short)bfr(dw2[(long)k * 256 + n]);
    } else if (b < 21504) {
        int i = (b - 20992) * 256 + t; int n = i >> 10, k = i & 1023;
        dwt3h[i] = (short)bfr(dw3[(long)k * 128 + n]);
    } else if (b < 22016) {
        int i = (b - 21504) * 256 + t;
        float x = cb[i]; unsigned short h = bfr(x);
        cbh[i] = (short)h; cbl[i] = (short)bfr(x - bff(h));
    } else {
        int i = (b - 22016) * 256 + t; if (i < 2048) zbuf[i] = 0.f;
    }
}

__global__ void wsplitT(const float* __restrict__ p1, short* __restrict__ hi,
                        short* __restrict__ lo)
{
    int i = blockIdx.x * 256 + threadIdx.x;
    if (i >= 262144) return;
    int n = i >> 11, k = i & 2047;
    float x = p1[(long)k * 128 + n];
    unsigned short h = bfr(x);
    hi[i] = (short)h;
    lo[i] = (short)bfr(x - bff(h));
}

__global__ void code_bias(const float* __restrict__ cb, const float* __restrict__ eb3,
                          float* __restrict__ bias2)
{
    int c = blockIdx.x * 4 + (threadIdx.x >> 6);
    int lane = threadIdx.x & 63;
    if (c >= 128) return;
    const f4* p = (const f4*)(cb + (long)c * 1024);
    const f4* e = (const f4*)eb3;
    float s2 = 0.f, su = 0.f;
#pragma unroll
    for (int q = 0; q < 4; ++q) {
        f4 v = p[q * 64 + lane];
        f4 w = e[q * 64 + lane];
        s2 += (v[0]*v[0] + v[1]*v[1]) + (v[2]*v[2] + v[3]*v[3]);
        su += (v[0]*w[0] + v[1]*w[1]) + (v[2]*w[2] + v[3]*w[3]);
    }
#pragma unroll
    for (int sh = 32; sh; sh >>= 1) {
        s2 += __shfl_xor(s2, sh, 64);
        su += __shfl_xor(su, sh, 64);
    }
    if (lane == 0) bias2[c] = s2 - 2.f * su;
}

__global__ __launch_bounds__(256)
void d1_gather(const float* __restrict__ CD, const int* __restrict__ idx,
               const float* __restrict__ db1, const float* __restrict__ dg1,
               const float* __restrict__ dbt1, short* __restrict__ out, float bns)
{
    int m = blockIdx.x * 4 + (threadIdx.x >> 6);
    int lane = threadIdx.x & 63;
    if (m >= 50176) return;
    int b = m / 196, rem = m - b * 196;
    int oi = rem / 14, oj = rem - oi * 14;
    float2 acc[4];
#pragma unroll
    for (int q = 0; q < 4; ++q) acc[q] = make_float2(0.f, 0.f);
#pragma unroll
    for (int t = 0; t < 4; ++t) {
        int ii = oi - 1 + (t >> 1), jj = oj - 1 + (t & 1);
        if (ii >= 0 && ii < 13 && jj >= 0 && jj < 13) {
            int c = idx[(b * 13 + ii) * 13 + jj];
            const float2* p = (const float2*)(CD + ((long)c * 2048 + t * 512));
#pragma unroll
            for (int q = 0; q < 4; ++q) {
                float2 v = p[lane + 64 * q];
                acc[q].x += v.x; acc[q].y += v.y;
            }
        }
    }
#pragma unroll
    for (int q = 0; q < 4; ++q) {
        int n = 2 * (lane + 64 * q);
        float v0 = fmaxf(dg1[n]     * ((acc[q].x + db1[n])     * bns) + dbt1[n],     0.f);
        float v1 = fmaxf(dg1[n + 1] * ((acc[q].y + db1[n + 1]) * bns) + dbt1[n + 1], 0.f);
        short2 s2v;
        s2v.x = (short)bfr(v0); s2v.y = (short)bfr(v1);
        ((short2*)out)[(long)m * 256 + lane + 64 * q] = s2v;
    }
}

__global__ void gather_rows(const float* __restrict__ cb, const int* __restrict__ idx,
                            float* __restrict__ q)
{
    int m = blockIdx.x;
    int c = idx[m];
    const f4* src = (const f4*)(cb + (long)c * 1024);
    f4* dst = (f4*)(q + (long)m * 1024);
    dst[threadIdx.x] = src[threadIdx.x];
}

__global__ void finalize2(const double* __restrict__ s, float* __restrict__ loss)
{
    if (threadIdx.x == 0)
        loss[0] = (float)(s[0] / 8388608.0 + 1.25 * ((s[1] + s[2]) / 44302336.0));
}

__global__ void vq_mean_fin(const float* __restrict__ colsum,
                            const float* __restrict__ mask, float* __restrict__ o)
{
    __shared__ float red[128];
    int b = blockIdx.x;
    int d = threadIdx.x;
    red[d] = mask[b * 256 + d] + mask[b * 256 + 128 + d];
    __syncthreads();
    for (int h = 64; h; h >>= 1) { if (d < h) red[d] += red[d + h]; __syncthreads(); }
    o[b * 128 + d] = colsum[b * 128 + d] / red[0];
}

extern "C" void kernel_launch(void* const* d_in, const int* in_sizes, int n_in,
                              void* d_out, int out_size, void* d_ws, size_t ws_size,
                              hipStream_t stream)
{
    const float* x    = (const float*)d_in[0];
    const float* mask = (const float*)d_in[1];
    const float* cb   = (const float*)d_in[2];
    const float* ew1 = (const float*)d_in[3];
    const float* eb1 = (const float*)d_in[4];
    const float* eg1 = (const float*)d_in[5];
    const float* ebt1= (const float*)d_in[6];
    const float* ew2 = (const float*)d_in[7];
    const float* eb2 = (const float*)d_in[8];
    const float* eg2 = (const float*)d_in[9];
    const float* ebt2= (const float*)d_in[10];
    const float* ew3 = (const float*)d_in[11];
    const float* eb3 = (const float*)d_in[12];
    const float* dw1 = (const float*)d_in[13];
    const float* db1 = (const float*)d_in[14];
    const float* dg1 = (const float*)d_in[15];
    const float* dbt1= (const float*)d_in[16];
    const float* dw2 = (const float*)d_in[17];
    const float* db2 = (const float*)d_in[18];
    const float* dg2 = (const float*)d_in[19];
    const float* dbt2= (const float*)d_in[20];
    const float* dw3 = (const float*)d_in[21];
    const float* db3 = (const float*)d_in[22];

    float* out = (float*)d_out;
    float* o_vqmean = out;
    float* o_vqx    = out + 32768;
    float* o_xe     = out + 8421376;
    float* o_q      = out + 52723712;
    float* o_loss   = out + 97026048;

    float* base;
    if (ws_size >= (size_t)WS_FLOATS * 4) {
        base = (float*)d_ws;
    } else {
        void* p = nullptr;
        hipGetSymbolAddress(&p, HIP_SYMBOL(g_fallback));
        base = (float*)p;
    }

    float* cur = base;
    short* h1h = (short*)cur; cur += 7372800;
    short* h1l = (short*)cur; cur += 7372800;
    short* h2h = (short*)cur; cur += 12845056;
    short* h2l = (short*)cur; cur += 12845056;
    short* d1o = (short*)cur; cur += 12845056;
    short* d2o = (short*)cur; cur += 7372800;
    short* ewt1h = (short*)cur; cur += 65536;
    short* ewt1l = (short*)cur; cur += 65536;
    short* ewt2h = (short*)cur; cur += 262144;
    short* ewt2l = (short*)cur; cur += 262144;
    short* ewt3h = (short*)cur; cur += 1048576;
    short* dwt1Th = (short*)cur; cur += 1048576;
    short* dwt1Tl = (short*)cur; cur += 1048576;
    short* dwt2h = (short*)cur; cur += 262144;
    short* dwt3h = (short*)cur; cur += 65536;
    short* cbh   = (short*)cur; cur += 65536;
    short* cbl   = (short*)cur; cur += 65536;
    float* P1raw = cur; cur += 262144;
    short* wvh   = (short*)cur; cur += 131072;
    short* wvl   = (short*)cur; cur += 131072;
    float* CDt   = cur; cur += 262144;
    float* bias2 = cur; cur += 128;
    float* zbuf  = cur; cur += 2048;
    int* idxb = (int*)cur; cur += 43264;
    float* colsum = cur; cur += 32768;
    double* sdbl = (double*)cur; cur += 16;   // [0]=recon [1]=fn [2]=best

    const float bns = (float)(1.0 / sqrt(1.0 + 1e-3));

    // dynamic-LDS opt-ins
    hipFuncSetAttribute(reinterpret_cast<const void*>(&gemm256<3>),
                        hipFuncAttributeMaxDynamicSharedMemorySize, 131072);
    hipFuncSetAttribute(reinterpret_cast<const void*>(&gemm256<1>),
                        hipFuncAttributeMaxDynamicSharedMemorySize, 131072);
    hipFuncSetAttribute(reinterpret_cast<const void*>(&e2_gemm),
                        hipFuncAttributeMaxDynamicSharedMemorySize, 98304);

    // ---- zero accumulators + prep ----
    hipMemsetAsync(colsum, 0, 32768 * sizeof(float), stream);
    hipMemsetAsync(sdbl, 0, 3 * sizeof(double), stream);
    prep_all<<<22024, 256, 0, stream>>>(ew1, ew2, ew3, dw1, dw2, dw3, cb,
        ewt1h, ewt1l, ewt2h, ewt2l, ewt3h, dwt1Th, dwt1Tl, dwt2h, dwt3h,
        cbh, cbl, zbuf);
    code_bias<<<32, 256, 0, stream>>>(cb, eb3, bias2);

    // ---- folds ----
    mfma_conv<2, 0, 0, 0><<<16, 256, 0, stream>>>(
        ew3, nullptr, cbh, cbl, zbuf, nullptr, nullptr, P1raw, nullptr, nullptr,
        nullptr, nullptr, nullptr,
        2, 2050, 1024, 10, 2048, 2048, 128, 1024, 0, 0, bns);
    wsplitT<<<1024, 256, 0, stream>>>(P1raw, wvh, wvl);
    mfma_conv<2, 0, 0, 0><<<16, 256, 0, stream>>>(
        cb, nullptr, dwt1Th, dwt1Tl, zbuf, nullptr, nullptr, CDt, nullptr, nullptr,
        nullptr, nullptr, nullptr,
        2, 130, 1024, 10, 128, 128, 2048, 1024, 0, 4, bns);

    // ---- encoder ----
    mfma_conv<2, 0, 1, 1><<<900, 256, 0, stream>>>(
        x, nullptr, ewt1h, ewt1l, eb1, eg1, ebt1, h1h, h1l, nullptr,
        nullptr, nullptr, nullptr,
        16, 16, 128, 7, 225, 15, 256, 512, 0, 1, bns);
    // E2: 256x128 deep-pipelined split (4-phase read-ahead)
    e2_gemm<<<784, 512, 98304, stream>>>(
        h1h, h1l, ewt2h, ewt2l, eb2, eg2, ebt2, h2h, h2l, bns);
    // E3: 256^2 deep-pipelined, 4-phase read-ahead (x_encode fp32 + fn-sum)
    gemm256<3><<<676, 512, 131072, stream>>>(
        h2h, ewt3h, eb3, nullptr, nullptr, o_xe, sdbl + 1, (const short*)zbuf,
        14, 14, 169, 13, 1024, 2048, 0, 2, bns);

    // ---- VQ: folded dist + argmin + best-sum ----
    mfma_conv<2, 1, 2, 0><<<338, 256, 0, stream>>>(
        h2h, h2l, wvh, wvl, bias2, nullptr, nullptr, nullptr, nullptr, idxb,
        nullptr, nullptr, sdbl + 2,
        14, 14, 512, 9, 169, 13, 128, 2048, 0, 0, bns);
    gather_rows<<<43264, 256, 0, stream>>>(cb, idxb, o_q);

    // ---- decoder ----
    d1_gather<<<12544, 256, 0, stream>>>(CDt, idxb, db1, dg1, dbt1, d1o, bns);
    // D2: 256^2 deep-pipelined, 4-phase read-ahead (bn-relu bf16 out)
    gemm256<1><<<225, 512, 131072, stream>>>(
        d1o, dwt2h, db2, dg2, dbt2, d2o, nullptr, (const short*)zbuf,
        14, 14, 225, 15, 256, 2048, -1, 0, bns);
    // D3: vq_x + recon-sum + colsum fused (128^2 template)
    mfma_conv<1, 2, 4, 0><<<512, 256, 0, stream>>>(
        d2o, nullptr, dwt3h, nullptr, db3, nullptr, nullptr, o_vqx, nullptr, nullptr,
        x, colsum, sdbl + 0,
        15, 15, 256, 8, 256, 16, 128, 1024, -1, 0, bns);

    // ---- outputs ----
    vq_mean_fin<<<256, 128, 0, stream>>>(colsum, mask, o_vqmean);
    finalize2<<<1, 64, 0, stream>>>(sdbl, o_loss);
}

// Round 12
// 883.811 us; speedup vs baseline: 1.0482x; 1.0482x over previous
//
#include <hip/hip_runtime.h>
#include <math.h>

typedef float f4 __attribute__((ext_vector_type(4)));
typedef short s8 __attribute__((ext_vector_type(8)));

#define WS_FLOATS 66000000L
__device__ float g_fallback[WS_FLOATS];

__device__ __forceinline__ f4 ldg4(const float* p) { return *(const f4*)p; }

__device__ __forceinline__ unsigned short bfr(float x) {   // fp32 -> bf16 RNE
    unsigned int u = __float_as_uint(x);
    u += 0x7fffu + ((u >> 16) & 1u);
    return (unsigned short)(u >> 16);
}
__device__ __forceinline__ float bff(unsigned short h) {
    return __uint_as_float(((unsigned int)h) << 16);
}
__device__ __forceinline__ s8 z8() { s8 z = {0,0,0,0,0,0,0,0}; return z; }

__device__ __forceinline__ void split8(const f4& x0, const f4& x1, s8& hi, s8& lo) {
#pragma unroll
    for (int e = 0; e < 4; ++e) {
        unsigned short h0 = bfr(x0[e]);
        hi[e] = (short)h0; lo[e] = (short)bfr(x0[e] - bff(h0));
        unsigned short h1 = bfr(x1[e]);
        hi[e + 4] = (short)h1; lo[e + 4] = (short)bfr(x1[e] - bff(h1));
    }
}

// ============================================================
// Coalesced 64x64 LDS-tiled transpose: src fp32 [K][N] -> dst bf16 [N][K]
// (hi, optional lo). Reads/writes fully coalesced; padded LDS = conflict-free.
// ============================================================
__device__ __forceinline__ void tpose64(const float* __restrict__ src,
                                        short* __restrict__ hi,
                                        short* __restrict__ lo,
                                        int K, int N, int tileId, int tid)
{
    __shared__ float ld[64][65];
    const int nt = N >> 6;
    const int k0 = (tileId / nt) << 6, n0 = (tileId % nt) << 6;
#pragma unroll
    for (int i = 0; i < 16; ++i) {
        int idx = tid + (i << 8);
        int r = idx >> 6, c = idx & 63;
        ld[r][c] = src[(long)(k0 + r) * N + n0 + c];
    }
    __syncthreads();
#pragma unroll
    for (int i = 0; i < 16; ++i) {
        int idx = tid + (i << 8);
        int nr = idx >> 6, kc = idx & 63;
        float x = ld[kc][nr];
        unsigned short h = bfr(x);
        long o = (long)(n0 + nr) * K + k0 + kc;
        hi[o] = (short)h;
        if (lo) lo[o] = (short)bfr(x - bff(h));
    }
}

// all weight transposes + codebook split + zbuf zero, coalesced
__global__ __launch_bounds__(256)
void tpose_all(const float* __restrict__ ew1, const float* __restrict__ ew2,
               const float* __restrict__ ew3, const float* __restrict__ dw1,
               const float* __restrict__ dw2, const float* __restrict__ dw3,
               const float* __restrict__ cb,
               short* __restrict__ ewt1h, short* __restrict__ ewt1l,
               short* __restrict__ ewt2h, short* __restrict__ ewt2l,
               short* __restrict__ ewt3h,
               short* __restrict__ dwt1Th, short* __restrict__ dwt1Tl,
               short* __restrict__ dwt2h, short* __restrict__ dwt3h,
               short* __restrict__ cbh, short* __restrict__ cbl,
               float* __restrict__ zbuf)
{
    int b = blockIdx.x, t = threadIdx.x;
    if (b < 32) {
        tpose64(ew1, ewt1h, ewt1l, 512, 256, b, t);
    } else if (b < 160) {
        tpose64(ew2, ewt2h, ewt2l, 1024, 512, b - 32, t);
    } else if (b < 672) {
        tpose64(ew3, ewt3h, nullptr, 2048, 1024, b - 160, t);
    } else if (b < 1184) {
        int r = b - 672; int tt = r >> 7; int tile = r & 127;
        tpose64(dw1 + (long)tt * 524288, dwt1Th + (long)tt * 524288,
                dwt1Tl + (long)tt * 524288, 1024, 512, tile, t);
    } else if (b < 1312) {
        tpose64(dw2, dwt2h, nullptr, 2048, 256, b - 1184, t);
    } else if (b < 1344) {
        tpose64(dw3, dwt3h, nullptr, 1024, 128, b - 1312, t);
    } else if (b < 1856) {
        int i = (b - 1344) * 256 + t;
        float x = cb[i]; unsigned short h = bfr(x);
        cbh[i] = (short)h; cbl[i] = (short)bfr(x - bff(h));
    } else {
#pragma unroll
        for (int q = 0; q < 8; ++q) zbuf[t + 256 * q] = 0.f;
    }
}

// P1raw [2048][128] fp32 -> wv [128][2048] bf16 hi/lo (coalesced)
__global__ __launch_bounds__(256)
void tposeP1(const float* __restrict__ p1, short* __restrict__ hi,
             short* __restrict__ lo)
{
    tpose64(p1, hi, lo, 2048, 128, blockIdx.x, threadIdx.x);
}

// ============================================================
// gemm256: 256x256-tile 8-wave plain-bf16 implicit-GEMM conv with
// counted-vmcnt deep pipeline (A and B both via global_load_lds). [R8 form]
// ============================================================
template<int EPI>
__global__ __launch_bounds__(512, 2)
void gemm256(const short* __restrict__ aSrc, const short* __restrict__ wHi,
             const float* __restrict__ bias, const float* __restrict__ gamma,
             const float* __restrict__ beta, void* __restrict__ oHi,
             double* __restrict__ sacc, const short* __restrict__ zsrc,
             int IH, int IW, int OHOW, int OW, int N, int K, int off,
             int ntShift, float bns)
{
    extern __shared__ short smem[];

    const int tid = threadIdx.x;
    const int w = tid >> 6;
    const int l = tid & 63;
    const int lr = l >> 3;
    const int lc = l & 7;
    const int fr = l & 15, fq = l >> 4;
    const int wm = (w >> 2) * 128;
    const int wn = (w & 3) * 64;

    int m0, n0;
    {
        const int nwg = gridDim.x;
        const int bid = blockIdx.x;
        const int q = nwg >> 3, r = nwg & 7;
        const int xcd = bid & 7, c = bid >> 3;
        const int wg = (xcd < r ? xcd * (q + 1) : r * (q + 1) + (xcd - r) * q) + c;
        const int NTm1 = (1 << ntShift) - 1;
        m0 = (wg >> ntShift) * 256;
        n0 = (wg & NTm1) * 256;
    }

    int bOff[4], oiA[4], ojA[4], bRowB[4];
#pragma unroll
    for (int i = 0; i < 4; ++i) {
        int row = (w << 5) + (i << 3) + lr;
        int m = m0 + row;
        int b = m / OHOW; int rem = m - b * OHOW;
        oiA[i] = rem / OW; ojA[i] = rem - oiA[i] * OW;
        bOff[i] = b * IH * IW;
        bRowB[i] = (n0 + row) * K;
    }
    const int swz = (lc ^ lr) << 3;

    auto stage = [&](int sel, int kc) {
        short* Ab = smem + sel * 16384;
        short* Bb = smem + 32768 + sel * 16384;
        const int t = kc >> 9;
        const int ci = (kc & 511) + swz;
        const int di = (t >> 1) + off, dj = (t & 1) + off;
#pragma unroll
        for (int i = 0; i < 4; ++i) {
            int ii = oiA[i] + di, jj = ojA[i] + dj;
            bool v = (ii >= 0) && (ii < IH) && (jj >= 0) && (jj < IW);
            const short* sA = v ? aSrc + (long)(bOff[i] + ii * IW + jj) * 512 + ci
                                : zsrc + (l << 3);
            __builtin_amdgcn_global_load_lds(
                (const __attribute__((address_space(1))) void*)sA,
                (__attribute__((address_space(3))) void*)(Ab + (((w << 5) + (i << 3)) * 64)),
                16, 0, 0);
            const short* sB = wHi + bRowB[i] + kc + swz;
            __builtin_amdgcn_global_load_lds(
                (const __attribute__((address_space(1))) void*)sB,
                (__attribute__((address_space(3))) void*)(Bb + (((w << 5) + (i << 3)) * 64)),
                16, 0, 0);
        }
    };

    f4 acc[8][4];
#pragma unroll
    for (int a = 0; a < 8; ++a)
#pragma unroll
        for (int b = 0; b < 4; ++b) acc[a][b] = (f4){0.f, 0.f, 0.f, 0.f};

    const int NT = K >> 6;
    stage(0, 0);
    stage(1, 64);

    for (int t = 0; t < NT; ++t) {
        const int sel = t & 1;
        const short* Ab = smem + sel * 16384;
        const short* Bb = smem + 32768 + sel * 16384;

        if (t < NT - 1) asm volatile("s_waitcnt vmcnt(8)" ::: "memory");
        else            asm volatile("s_waitcnt vmcnt(0)" ::: "memory");
        __builtin_amdgcn_s_barrier();
        __builtin_amdgcn_sched_barrier(0);

        s8 af[8], bf[4];
#pragma unroll
        for (int mf = 0; mf < 8; ++mf) {
            int row = wm + mf * 16 + fr;
            int c = fq ^ (row & 7);
            af[mf] = *(const s8*)&Ab[row * 64 + (c << 3)];
        }
#pragma unroll
        for (int nf = 0; nf < 4; ++nf) {
            int row = wn + nf * 16 + fr;
            int c = fq ^ (row & 7);
            bf[nf] = *(const s8*)&Bb[row * 64 + (c << 3)];
        }
        asm volatile("s_waitcnt lgkmcnt(0)" ::: "memory");
        __builtin_amdgcn_sched_barrier(0);
        __builtin_amdgcn_s_setprio(1);
#pragma unroll
        for (int mf = 0; mf < 8; ++mf)
#pragma unroll
            for (int nf = 0; nf < 4; ++nf)
                acc[mf][nf] = __builtin_amdgcn_mfma_f32_16x16x32_bf16(
                    af[mf], bf[nf], acc[mf][nf], 0, 0, 0);
        __builtin_amdgcn_s_setprio(0);

#pragma unroll
        for (int mf = 0; mf < 8; ++mf) {
            int row = wm + mf * 16 + fr;
            int c = (4 + fq) ^ (row & 7);
            af[mf] = *(const s8*)&Ab[row * 64 + (c << 3)];
        }
#pragma unroll
        for (int nf = 0; nf < 4; ++nf) {
            int row = wn + nf * 16 + fr;
            int c = (4 + fq) ^ (row & 7);
            bf[nf] = *(const s8*)&Bb[row * 64 + (c << 3)];
        }
        asm volatile("s_waitcnt lgkmcnt(0)" ::: "memory");
        __builtin_amdgcn_sched_barrier(0);
        __builtin_amdgcn_s_barrier();
        __builtin_amdgcn_sched_barrier(0);
        if (t + 2 < NT) stage(sel, (t + 2) << 6);

        __builtin_amdgcn_s_setprio(1);
#pragma unroll
        for (int mf = 0; mf < 8; ++mf)
#pragma unroll
            for (int nf = 0; nf < 4; ++nf)
                acc[mf][nf] = __builtin_amdgcn_mfma_f32_16x16x32_bf16(
                    af[mf], bf[nf], acc[mf][nf], 0, 0, 0);
        __builtin_amdgcn_s_setprio(0);
    }

    if (EPI == 3) {
        float bi[4];
#pragma unroll
        for (int nf = 0; nf < 4; ++nf) bi[nf] = bias[n0 + wn + nf * 16 + fr];
        double tsum = 0.0;
#pragma unroll
        for (int mf = 0; mf < 8; ++mf)
#pragma unroll
            for (int j = 0; j < 4; ++j) {
                long gm = m0 + wm + mf * 16 + fq * 4 + j;
                float* orow = (float*)oHi + gm * (long)N + n0;
#pragma unroll
                for (int nf = 0; nf < 4; ++nf) {
                    float v = acc[mf][nf][j] + bi[nf];
                    orow[wn + nf * 16 + fr] = v;
                    tsum += (double)v * v;
                }
            }
        __syncthreads();
        double* rd = (double*)smem;
        rd[tid] = tsum; __syncthreads();
        for (int h = 256; h; h >>= 1) {
            if (tid < h) rd[tid] += rd[tid + h];
            __syncthreads();
        }
        if (tid == 0) atomicAdd(sacc, rd[0]);
    } else {
        float bi[4], ga[4], be[4];
#pragma unroll
        for (int nf = 0; nf < 4; ++nf) {
            int col = n0 + wn + nf * 16 + fr;
            bi[nf] = bias[col]; ga[nf] = gamma[col]; be[nf] = beta[col];
        }
#pragma unroll
        for (int mf = 0; mf < 8; ++mf)
#pragma unroll
            for (int j = 0; j < 4; ++j) {
                long gm = m0 + wm + mf * 16 + fq * 4 + j;
                short* orow = (short*)oHi + gm * (long)N + n0;
#pragma unroll
                for (int nf = 0; nf < 4; ++nf) {
                    float v = ga[nf] * ((acc[mf][nf][j] + bi[nf]) * bns) + be[nf];
                    orow[wn + nf * 16 + fr] = (short)bfr(fmaxf(v, 0.f));
                }
            }
    }
}

// ============================================================
// 128^2 template (proven) for split kernels, folds, VQ, and D3.
// ============================================================
template<int SPLIT, int ASRC, int EPI, int OUTF>
__global__ __launch_bounds__(256, 2)
void mfma_conv(const void* __restrict__ aHi, const void* __restrict__ aLo,
               const short* __restrict__ wHi, const short* __restrict__ wLo,
               const float* __restrict__ bias, const float* __restrict__ gamma,
               const float* __restrict__ beta,
               void* __restrict__ oHi, void* __restrict__ oLo,
               int* __restrict__ idxo,
               const float* __restrict__ xref, float* __restrict__ colsum,
               double* __restrict__ sacc,
               int IH, int IW, int Cin, int cinShift, int OHOW, int OW,
               int N, int K, int off, int ntShift, float bns)
{
    constexpr int PL = 128 * 64;
    constexpr int NPL = (SPLIT == 1) ? 3 : 4;
    __shared__ short smem[NPL * PL];
    short* Ah = smem;
    short* Al  = smem + PL;
    short* BhS = smem + 2 * PL;
    short* BlS = smem + 3 * PL;

    const int tid = threadIdx.x;
    const int lane = tid & 63, wid = tid >> 6;
    const int fr = lane & 15, fq = lane >> 4;
    const int wm = (wid >> 1) * 64, wn = (wid & 1) * 64;

    int m0, n0;
    {
        const int nwg = gridDim.x;
        const int bid = blockIdx.x;
        const int q = nwg >> 3, r = nwg & 7;
        const int xcd = bid & 7, c = bid >> 3;
        const int wg = (xcd < r ? xcd * (q + 1) : r * (q + 1) + (xcd - r) * q) + c;
        const int NTm1 = (1 << ntShift) - 1;
        m0 = (wg >> ntShift) * 128;
        n0 = (wg & NTm1) * 128;
    }

    const int sr = tid >> 1;
    const int skh = (tid & 1) << 5;

    long tapOff[4]; bool tv[4];
    {
        int m = m0 + sr;
        int b = m / OHOW; int rem = m - b * OHOW;
        int oi = rem / OW; int oj = rem - oi * OW;
#pragma unroll
        for (int t = 0; t < 4; ++t) {
            int ii = oi + (t >> 1) + off, jj = oj + (t & 1) + off;
            bool v = (ii >= 0) && (ii < IH) && (jj >= 0) && (jj < IW);
            tv[t] = v;
            tapOff[t] = ((long)b * IH + (v ? ii : 0)) * IW + (v ? jj : 0);
        }
    }

    f4 acc[4][4];
#pragma unroll
    for (int a = 0; a < 4; ++a)
#pragma unroll
        for (int b = 0; b < 4; ++b) acc[a][b] = (f4){0.f, 0.f, 0.f, 0.f};

    const short* wHrow = wHi + (long)(n0 + sr) * K;
    const short* wLrow = (SPLIT == 2) ? (wLo + (long)(n0 + sr) * K) : nullptr;

    const int swzW = (sr & 7) << 3;
    const int sbase = sr * 64;

    s8 rah[4], ral[4], rbh[4], rbl[4];
    f4 rax0[4], rax1[4];

    auto LOADREGS = [&](int kc) {
        const int kk = kc + skh;
        const int t = kk >> cinShift;
        const int ci = kk & (Cin - 1);
        const bool v = tv[t];
        if (ASRC == 0) {
            const float* p = (const float*)aHi + tapOff[t] * Cin + ci;
#pragma unroll
            for (int q = 0; q < 4; ++q) {
                rax0[q] = v ? ldg4(p + 8 * q) : (f4){0.f,0.f,0.f,0.f};
                rax1[q] = v ? ldg4(p + 8 * q + 4) : (f4){0.f,0.f,0.f,0.f};
            }
        } else if (ASRC == 1) {
            const short* ph = (const short*)aHi + tapOff[t] * Cin + ci;
            const short* pl = (const short*)aLo + tapOff[t] * Cin + ci;
#pragma unroll
            for (int q = 0; q < 4; ++q) {
                rah[q] = v ? *(const s8*)(ph + 8 * q) : z8();
                ral[q] = v ? *(const s8*)(pl + 8 * q) : z8();
            }
        } else {
            const short* ph = (const short*)aHi + tapOff[t] * Cin + ci;
#pragma unroll
            for (int q = 0; q < 4; ++q) rah[q] = v ? *(const s8*)(ph + 8 * q) : z8();
        }
        if (SPLIT == 2) {
#pragma unroll
            for (int q = 0; q < 4; ++q) {
                rbh[q] = *(const s8*)(wHrow + kc + skh + 8 * q);
                rbl[q] = *(const s8*)(wLrow + kc + skh + 8 * q);
            }
        }
    };

    auto STORE = [&]() {
        if (ASRC == 0) {
#pragma unroll
            for (int q = 0; q < 4; ++q) split8(rax0[q], rax1[q], rah[q], ral[q]);
        }
#pragma unroll
        for (int q = 0; q < 4; ++q) {
            int kx = (skh + 8 * q) ^ swzW;
            *(s8*)&Ah[sbase + kx] = rah[q];
            if (SPLIT == 2) {
                *(s8*)&Al[sbase + kx]  = ral[q];
                *(s8*)&BhS[sbase + kx] = rbh[q];
                *(s8*)&BlS[sbase + kx] = rbl[q];
            }
        }
    };

    auto stageB = [&](int bsel, int kc2) {
        short* bb = smem + (1 + bsel) * PL;
        const int rr0 = wid << 5;
#pragma unroll
        for (int i = 0; i < 4; ++i) {
            const int r = rr0 + 8 * i + (lane >> 3);
            const int c = lane & 7;
            const short* src = wHi + (long)(n0 + r) * K + kc2 + 8 * (c ^ (r & 7));
            __builtin_amdgcn_global_load_lds(
                (const __attribute__((address_space(1))) void*)src,
                (__attribute__((address_space(3))) void*)(bb + (rr0 + 8 * i) * 64),
                16, 0, 0);
        }
    };

    int bcur = 0;
    LOADREGS(0);
    if (SPLIT == 1) stageB(0, 0);

    for (int kc = 0; kc < K; kc += 64) {
        if (SPLIT == 1) {
            asm volatile("s_waitcnt lgkmcnt(0)" ::: "memory");
            __builtin_amdgcn_s_barrier();
            STORE();
            if (kc + 64 < K) {
                stageB(bcur ^ 1, kc + 64);
                asm volatile("s_waitcnt vmcnt(4)" ::: "memory");
            } else {
                asm volatile("s_waitcnt vmcnt(0)" ::: "memory");
            }
            __builtin_amdgcn_sched_barrier(0);
            asm volatile("s_waitcnt lgkmcnt(0)" ::: "memory");
            __builtin_amdgcn_s_barrier();
        } else {
            __syncthreads();
            STORE();
            __syncthreads();
        }
        if (kc + 64 < K) LOADREGS(kc + 64);

        const short* Bc = (SPLIT == 1) ? (smem + (1 + bcur) * PL) : BhS;

        __builtin_amdgcn_s_setprio(1);
#pragma unroll
        for (int ks = 0; ks < 2; ++ks) {
            const int colk = ks * 32 + fq * 8;
            s8 afh[4], afl[4], bfh[4], bfl[4];
#pragma unroll
            for (int mf = 0; mf < 4; ++mf) {
                int ar = wm + mf * 16 + fr;
                int ai = ar * 64 + (colk ^ ((ar & 7) << 3));
                afh[mf] = *(const s8*)&Ah[ai];
                if (SPLIT == 2) afl[mf] = *(const s8*)&Al[ai];
            }
#pragma unroll
            for (int nf = 0; nf < 4; ++nf) {
                int br = wn + nf * 16 + fr;
                int bi2 = br * 64 + (colk ^ ((br & 7) << 3));
                bfh[nf] = *(const s8*)&Bc[bi2];
                if (SPLIT == 2) bfl[nf] = *(const s8*)&BlS[bi2];
            }
#pragma unroll
            for (int mf = 0; mf < 4; ++mf)
#pragma unroll
                for (int nf = 0; nf < 4; ++nf) {
                    acc[mf][nf] = __builtin_amdgcn_mfma_f32_16x16x32_bf16(
                        afh[mf], bfh[nf], acc[mf][nf], 0, 0, 0);
                    if (SPLIT == 2) {
                        acc[mf][nf] = __builtin_amdgcn_mfma_f32_16x16x32_bf16(
                            afh[mf], bfl[nf], acc[mf][nf], 0, 0, 0);
                        acc[mf][nf] = __builtin_amdgcn_mfma_f32_16x16x32_bf16(
                            afl[mf], bfh[nf], acc[mf][nf], 0, 0, 0);
                    }
                }
        }
        __builtin_amdgcn_s_setprio(0);
        bcur ^= 1;
    }

    if (EPI == 2) {
        __syncthreads();
        float* pbv = (float*)smem;
        int*   piv = (int*)((float*)smem + 256);
        float cnv[4];
#pragma unroll
        for (int nf = 0; nf < 4; ++nf) cnv[nf] = bias[n0 + wn + nf * 16 + fr];
#pragma unroll
        for (int mf = 0; mf < 4; ++mf)
#pragma unroll
            for (int j = 0; j < 4; ++j) {
                float best = 3.4e38f; int bi = 0;
#pragma unroll
                for (int nf = 0; nf < 4; ++nf) {
                    float d = cnv[nf] - 2.0f * acc[mf][nf][j];
                    int col = wn + nf * 16 + fr;
                    if (d < best) { best = d; bi = col; }
                }
#pragma unroll
                for (int sh = 1; sh <= 8; sh <<= 1) {
                    float ov = __shfl_xor(best, sh, 64);
                    int ob = __shfl_xor(bi, sh, 64);
                    if (ov < best || (ov == best && ob < bi)) { best = ov; bi = ob; }
                }
                if (fr == 0) {
                    int r = wm + mf * 16 + fq * 4 + j;
                    pbv[(wid & 1) * 128 + r] = best;
                    piv[(wid & 1) * 128 + r] = bi;
                }
            }
        __syncthreads();
        double win = 0.0;
        if (tid < 128) {
            float b0 = pbv[tid], b1 = pbv[128 + tid];
            int i0 = piv[tid], i1 = piv[128 + tid];
            idxo[m0 + tid] = (b1 < b0) ? i1 : i0;
            win = (double)((b1 < b0) ? b1 : b0);
        }
        __syncthreads();
        double* rd = (double*)smem;
        rd[tid] = win; __syncthreads();
        for (int h = 128; h; h >>= 1) {
            if (tid < h) rd[tid] += rd[tid + h];
            __syncthreads();
        }
        if (tid == 0) atomicAdd(sacc, rd[0]);
        return;
    }

    float bi[4], ga[4], be[4];
#pragma unroll
    for (int nf = 0; nf < 4; ++nf) {
        int col = n0 + wn + nf * 16 + fr;
        bi[nf] = bias[col];
        if (EPI == 1) { ga[nf] = gamma[col]; be[nf] = beta[col]; }
    }
    double tsum = 0.0;
    float csum[4] = {0.f, 0.f, 0.f, 0.f};
#pragma unroll
    for (int mf = 0; mf < 4; ++mf)
#pragma unroll
        for (int j = 0; j < 4; ++j) {
            long gm = m0 + wm + mf * 16 + fq * 4 + j;
#pragma unroll
            for (int nf = 0; nf < 4; ++nf) {
                int col = n0 + wn + nf * 16 + fr;
                float vv = acc[mf][nf][j] + bi[nf];
                if (EPI == 1) {
                    vv = ga[nf] * (vv * bns) + be[nf];
                    vv = fmaxf(vv, 0.f);
                }
                long o = gm * (long)N + col;
                if (OUTF == 0) {
                    ((float*)oHi)[o] = vv;
                } else if (OUTF == 2) {
                    ((short*)oHi)[o] = (short)bfr(vv);
                } else {
                    unsigned short h = bfr(vv);
                    ((short*)oHi)[o] = (short)h;
                    ((short*)oLo)[o] = (short)bfr(vv - bff(h));
                }
                if (EPI == 3) tsum += (double)vv * vv;
                if (EPI == 4) {
                    float d = vv - xref[o];
                    tsum += (double)d * d;
                    csum[nf] += vv;
                }
            }
        }
    if (EPI == 4) {
        int bb128 = (m0 >> 8) * 128;
#pragma unroll
        for (int nf = 0; nf < 4; ++nf)
            atomicAdd(&colsum[bb128 + n0 + wn + nf * 16 + fr], csum[nf]);
    }
    if (EPI == 3 || EPI == 4) {
        __syncthreads();
        double* rd = (double*)smem;
        rd[tid] = tsum; __syncthreads();
        for (int h = 128; h; h >>= 1) {
            if (tid < h) rd[tid] += rd[tid + h];
            __syncthreads();
        }
        if (tid == 0) atomicAdd(sacc, rd[0]);
    }
}

// bias2[c] = ||cb_c||^2 - 2*dot(eb3, cb_c)
__global__ void code_bias(const float* __restrict__ cb, const float* __restrict__ eb3,
                          float* __restrict__ bias2)
{
    int c = blockIdx.x * 4 + (threadIdx.x >> 6);
    int lane = threadIdx.x & 63;
    if (c >= 128) return;
    const f4* p = (const f4*)(cb + (long)c * 1024);
    const f4* e = (const f4*)eb3;
    float s2 = 0.f, su = 0.f;
#pragma unroll
    for (int q = 0; q < 4; ++q) {
        f4 v = p[q * 64 + lane];
        f4 w = e[q * 64 + lane];
        s2 += (v[0]*v[0] + v[1]*v[1]) + (v[2]*v[2] + v[3]*v[3]);
        su += (v[0]*w[0] + v[1]*w[1]) + (v[2]*w[2] + v[3]*w[3]);
    }
#pragma unroll
    for (int sh = 32; sh; sh >>= 1) {
        s2 += __shfl_xor(s2, sh, 64);
        su += __shfl_xor(su, sh, 64);
    }
    if (lane == 0) bias2[c] = s2 - 2.f * su;
}

// D1 via folded codebook table
__global__ __launch_bounds__(256)
void d1_gather(const float* __restrict__ CD, const int* __restrict__ idx,
               const float* __restrict__ db1, const float* __restrict__ dg1,
               const float* __restrict__ dbt1, short* __restrict__ out, float bns)
{
    int m = blockIdx.x * 4 + (threadIdx.x >> 6);
    int lane = threadIdx.x & 63;
    if (m >= 50176) return;
    int b = m / 196, rem = m - b * 196;
    int oi = rem / 14, oj = rem - oi * 14;
    float2 acc[4];
#pragma unroll
    for (int q = 0; q < 4; ++q) acc[q] = make_float2(0.f, 0.f);
#pragma unroll
    for (int t = 0; t < 4; ++t) {
        int ii = oi - 1 + (t >> 1), jj = oj - 1 + (t & 1);
        if (ii >= 0 && ii < 13 && jj >= 0 && jj < 13) {
            int c = idx[(b * 13 + ii) * 13 + jj];
            const float2* p = (const float2*)(CD + ((long)c * 2048 + t * 512));
#pragma unroll
            for (int q = 0; q < 4; ++q) {
                float2 v = p[lane + 64 * q];
                acc[q].x += v.x; acc[q].y += v.y;
            }
        }
    }
#pragma unroll
    for (int q = 0; q < 4; ++q) {
        int n = 2 * (lane + 64 * q);
        float v0 = fmaxf(dg1[n]     * ((acc[q].x + db1[n])     * bns) + dbt1[n],     0.f);
        float v1 = fmaxf(dg1[n + 1] * ((acc[q].y + db1[n + 1]) * bns) + dbt1[n + 1], 0.f);
        short2 s2v;
        s2v.x = (short)bfr(v0); s2v.y = (short)bfr(v1);
        ((short2*)out)[(long)m * 256 + lane + 64 * q] = s2v;
    }
}

__global__ void gather_rows(const float* __restrict__ cb, const int* __restrict__ idx,
                            float* __restrict__ q)
{
    int m = blockIdx.x;
    int c = idx[m];
    const f4* src = (const f4*)(cb + (long)c * 1024);
    f4* dst = (f4*)(q + (long)m * 1024);
    dst[threadIdx.x] = src[threadIdx.x];
}

__global__ void finalize2(const double* __restrict__ s, float* __restrict__ loss)
{
    if (threadIdx.x == 0)
        loss[0] = (float)(s[0] / 8388608.0 + 1.25 * ((s[1] + s[2]) / 44302336.0));
}

__global__ void vq_mean_fin(const float* __restrict__ colsum,
                            const float* __restrict__ mask, float* __restrict__ o)
{
    __shared__ float red[128];
    int b = blockIdx.x;
    int d = threadIdx.x;
    red[d] = mask[b * 256 + d] + mask[b * 256 + 128 + d];
    __syncthreads();
    for (int h = 64; h; h >>= 1) { if (d < h) red[d] += red[d + h]; __syncthreads(); }
    o[b * 128 + d] = colsum[b * 128 + d] / red[0];
}

extern "C" void kernel_launch(void* const* d_in, const int* in_sizes, int n_in,
                              void* d_out, int out_size, void* d_ws, size_t ws_size,
                              hipStream_t stream)
{
    const float* x    = (const float*)d_in[0];
    const float* mask = (const float*)d_in[1];
    const float* cb   = (const float*)d_in[2];
    const float* ew1 = (const float*)d_in[3];
    const float* eb1 = (const float*)d_in[4];
    const float* eg1 = (const float*)d_in[5];
    const float* ebt1= (const float*)d_in[6];
    const float* ew2 = (const float*)d_in[7];
    const float* eb2 = (const float*)d_in[8];
    const float* eg2 = (const float*)d_in[9];
    const float* ebt2= (const float*)d_in[10];
    const float* ew3 = (const float*)d_in[11];
    const float* eb3 = (const float*)d_in[12];
    const float* dw1 = (const float*)d_in[13];
    const float* db1 = (const float*)d_in[14];
    const float* dg1 = (const float*)d_in[15];
    const float* dbt1= (const float*)d_in[16];
    const float* dw2 = (const float*)d_in[17];
    const float* db2 = (const float*)d_in[18];
    const float* dg2 = (const float*)d_in[19];
    const float* dbt2= (const float*)d_in[20];
    const float* dw3 = (const float*)d_in[21];
    const float* db3 = (const float*)d_in[22];

    float* out = (float*)d_out;
    float* o_vqmean = out;
    float* o_vqx    = out + 32768;
    float* o_xe     = out + 8421376;
    float* o_q      = out + 52723712;
    float* o_loss   = out + 97026048;

    float* base;
    if (ws_size >= (size_t)WS_FLOATS * 4) {
        base = (float*)d_ws;
    } else {
        void* p = nullptr;
        hipGetSymbolAddress(&p, HIP_SYMBOL(g_fallback));
        base = (float*)p;
    }

    float* cur = base;
    short* h1h = (short*)cur; cur += 7372800;
    short* h1l = (short*)cur; cur += 7372800;
    short* h2h = (short*)cur; cur += 12845056;
    short* h2l = (short*)cur; cur += 12845056;
    short* d1o = (short*)cur; cur += 12845056;
    short* d2o = (short*)cur; cur += 7372800;
    short* ewt1h = (short*)cur; cur += 65536;
    short* ewt1l = (short*)cur; cur += 65536;
    short* ewt2h = (short*)cur; cur += 262144;
    short* ewt2l = (short*)cur; cur += 262144;
    short* ewt3h = (short*)cur; cur += 1048576;
    short* dwt1Th = (short*)cur; cur += 1048576;
    short* dwt1Tl = (short*)cur; cur += 1048576;
    short* dwt2h = (short*)cur; cur += 262144;
    short* dwt3h = (short*)cur; cur += 65536;
    short* cbh   = (short*)cur; cur += 65536;
    short* cbl   = (short*)cur; cur += 65536;
    float* P1raw = cur; cur += 262144;
    short* wvh   = (short*)cur; cur += 131072;
    short* wvl   = (short*)cur; cur += 131072;
    float* CDt   = cur; cur += 262144;
    float* bias2 = cur; cur += 128;
    float* zbuf  = cur; cur += 2048;
    int* idxb = (int*)cur; cur += 43264;
    float* colsum = cur; cur += 32768;
    double* sdbl = (double*)cur; cur += 16;   // [0]=recon [1]=fn [2]=best

    const float bns = (float)(1.0 / sqrt(1.0 + 1e-3));

    // dynamic-LDS opt-ins
    hipFuncSetAttribute(reinterpret_cast<const void*>(&gemm256<3>),
                        hipFuncAttributeMaxDynamicSharedMemorySize, 131072);
    hipFuncSetAttribute(reinterpret_cast<const void*>(&gemm256<1>),
                        hipFuncAttributeMaxDynamicSharedMemorySize, 131072);

    // ---- zero accumulators + prep (coalesced transposes) ----
    hipMemsetAsync(colsum, 0, 32768 * sizeof(float), stream);
    hipMemsetAsync(sdbl, 0, 3 * sizeof(double), stream);
    tpose_all<<<1857, 256, 0, stream>>>(ew1, ew2, ew3, dw1, dw2, dw3, cb,
        ewt1h, ewt1l, ewt2h, ewt2l, ewt3h, dwt1Th, dwt1Tl, dwt2h, dwt3h,
        cbh, cbl, zbuf);
    code_bias<<<32, 256, 0, stream>>>(cb, eb3, bias2);

    // ---- folds ----
    mfma_conv<2, 0, 0, 0><<<16, 256, 0, stream>>>(
        ew3, nullptr, cbh, cbl, zbuf, nullptr, nullptr, P1raw, nullptr, nullptr,
        nullptr, nullptr, nullptr,
        2, 2050, 1024, 10, 2048, 2048, 128, 1024, 0, 0, bns);
    tposeP1<<<64, 256, 0, stream>>>(P1raw, wvh, wvl);
    mfma_conv<2, 0, 0, 0><<<16, 256, 0, stream>>>(
        cb, nullptr, dwt1Th, dwt1Tl, zbuf, nullptr, nullptr, CDt, nullptr, nullptr,
        nullptr, nullptr, nullptr,
        2, 130, 1024, 10, 128, 128, 2048, 1024, 0, 4, bns);

    // ---- encoder ----
    mfma_conv<2, 0, 1, 1><<<900, 256, 0, stream>>>(
        x, nullptr, ewt1h, ewt1l, eb1, eg1, ebt1, h1h, h1l, nullptr,
        nullptr, nullptr, nullptr,
        16, 16, 128, 7, 225, 15, 256, 512, 0, 1, bns);
    mfma_conv<2, 1, 1, 1><<<1568, 256, 0, stream>>>(
        h1h, h1l, ewt2h, ewt2l, eb2, eg2, ebt2, h2h, h2l, nullptr,
        nullptr, nullptr, nullptr,
        15, 15, 256, 8, 196, 14, 512, 1024, 0, 2, bns);
    // E3: 256^2 deep-pipelined (x_encode fp32 out + fn-sum)
    gemm256<3><<<676, 512, 131072, stream>>>(
        h2h, ewt3h, eb3, nullptr, nullptr, o_xe, sdbl + 1, (const short*)zbuf,
        14, 14, 169, 13, 1024, 2048, 0, 2, bns);

    // ---- VQ: folded dist + argmin + best-sum ----
    mfma_conv<2, 1, 2, 0><<<338, 256, 0, stream>>>(
        h2h, h2l, wvh, wvl, bias2, nullptr, nullptr, nullptr, nullptr, idxb,
        nullptr, nullptr, sdbl + 2,
        14, 14, 512, 9, 169, 13, 128, 2048, 0, 0, bns);
    gather_rows<<<43264, 256, 0, stream>>>(cb, idxb, o_q);

    // ---- decoder ----
    d1_gather<<<12544, 256, 0, stream>>>(CDt, idxb, db1, dg1, dbt1, d1o, bns);
    // D2: 256^2 deep-pipelined (bn-relu bf16 out)
    gemm256<1><<<225, 512, 131072, stream>>>(
        d1o, dwt2h, db2, dg2, dbt2, d2o, nullptr, (const short*)zbuf,
        14, 14, 225, 15, 256, 2048, -1, 0, bns);
    // D3: vq_x + recon-sum + colsum fused (128^2 template)
    mfma_conv<1, 2, 4, 0><<<512, 256, 0, stream>>>(
        d2o, nullptr, dwt3h, nullptr, db3, nullptr, nullptr, o_vqx, nullptr, nullptr,
        x, colsum, sdbl + 0,
        15, 15, 256, 8, 256, 16, 128, 1024, -1, 0, bns);

    // ---- outputs ----
    vq_mean_fin<<<256, 128, 0, stream>>>(colsum, mask, o_vqmean);
    finalize2<<<1, 64, 0, stream>>>(sdbl, o_loss);
}

// Round 13
// 878.257 us; speedup vs baseline: 1.0548x; 1.0063x over previous
//
#include <hip/hip_runtime.h>
#include <math.h>

typedef float f4 __attribute__((ext_vector_type(4)));
typedef short s8 __attribute__((ext_vector_type(8)));

#define WS_FLOATS 66000000L
__device__ float g_fallback[WS_FLOATS];

__device__ __forceinline__ f4 ldg4(const float* p) { return *(const f4*)p; }

__device__ __forceinline__ unsigned short bfr(float x) {   // fp32 -> bf16 RNE
    unsigned int u = __float_as_uint(x);
    u += 0x7fffu + ((u >> 16) & 1u);
    return (unsigned short)(u >> 16);
}
__device__ __forceinline__ float bff(unsigned short h) {
    return __uint_as_float(((unsigned int)h) << 16);
}
__device__ __forceinline__ s8 z8() { s8 z = {0,0,0,0,0,0,0,0}; return z; }

__device__ __forceinline__ void split8(const f4& x0, const f4& x1, s8& hi, s8& lo) {
#pragma unroll
    for (int e = 0; e < 4; ++e) {
        unsigned short h0 = bfr(x0[e]);
        hi[e] = (short)h0; lo[e] = (short)bfr(x0[e] - bff(h0));
        unsigned short h1 = bfr(x1[e]);
        hi[e + 4] = (short)h1; lo[e + 4] = (short)bfr(x1[e] - bff(h1));
    }
}

// ============================================================
// Coalesced 64x64 LDS-tiled transpose: src fp32 [K][N] -> dst bf16 [N][K]
// ============================================================
__device__ __forceinline__ void tpose64(const float* __restrict__ src,
                                        short* __restrict__ hi,
                                        short* __restrict__ lo,
                                        int K, int N, int tileId, int tid)
{
    __shared__ float ld[64][65];
    const int nt = N >> 6;
    const int k0 = (tileId / nt) << 6, n0 = (tileId % nt) << 6;
#pragma unroll
    for (int i = 0; i < 16; ++i) {
        int idx = tid + (i << 8);
        int r = idx >> 6, c = idx & 63;
        ld[r][c] = src[(long)(k0 + r) * N + n0 + c];
    }
    __syncthreads();
#pragma unroll
    for (int i = 0; i < 16; ++i) {
        int idx = tid + (i << 8);
        int nr = idx >> 6, kc = idx & 63;
        float x = ld[kc][nr];
        unsigned short h = bfr(x);
        long o = (long)(n0 + nr) * K + k0 + kc;
        hi[o] = (short)h;
        if (lo) lo[o] = (short)bfr(x - bff(h));
    }
}

// all weight transposes + codebook split + zbuf zero + code_bias, coalesced
__global__ __launch_bounds__(256)
void tpose_all(const float* __restrict__ ew1, const float* __restrict__ ew2,
               const float* __restrict__ ew3, const float* __restrict__ dw1,
               const float* __restrict__ dw2, const float* __restrict__ dw3,
               const float* __restrict__ cb, const float* __restrict__ eb3,
               short* __restrict__ ewt1h, short* __restrict__ ewt1l,
               short* __restrict__ ewt2h, short* __restrict__ ewt2l,
               short* __restrict__ ewt3h,
               short* __restrict__ dwt1Th, short* __restrict__ dwt1Tl,
               short* __restrict__ dwt2h, short* __restrict__ dwt3h,
               short* __restrict__ cbh, short* __restrict__ cbl,
               float* __restrict__ zbuf, float* __restrict__ bias2)
{
    int b = blockIdx.x, t = threadIdx.x;
    if (b < 32) {
        tpose64(ew1, ewt1h, ewt1l, 512, 256, b, t);
    } else if (b < 160) {
        tpose64(ew2, ewt2h, ewt2l, 1024, 512, b - 32, t);
    } else if (b < 672) {
        tpose64(ew3, ewt3h, nullptr, 2048, 1024, b - 160, t);
    } else if (b < 1184) {
        int r = b - 672; int tt = r >> 7; int tile = r & 127;
        tpose64(dw1 + (long)tt * 524288, dwt1Th + (long)tt * 524288,
                dwt1Tl + (long)tt * 524288, 1024, 512, tile, t);
    } else if (b < 1312) {
        tpose64(dw2, dwt2h, nullptr, 2048, 256, b - 1184, t);
    } else if (b < 1344) {
        tpose64(dw3, dwt3h, nullptr, 1024, 128, b - 1312, t);
    } else if (b < 1856) {
        int i = (b - 1344) * 256 + t;
        float x = cb[i]; unsigned short h = bfr(x);
        cbh[i] = (short)h; cbl[i] = (short)bfr(x - bff(h));
    } else if (b < 1857) {
#pragma unroll
        for (int q = 0; q < 8; ++q) zbuf[t + 256 * q] = 0.f;
    } else {
        // code_bias: bias2[c] = ||cb_c||^2 - 2*dot(eb3, cb_c)
        int c = (b - 1857) * 4 + (t >> 6);
        int lane = t & 63;
        if (c < 128) {
            const f4* p = (const f4*)(cb + (long)c * 1024);
            const f4* e = (const f4*)eb3;
            float s2 = 0.f, su = 0.f;
#pragma unroll
            for (int q = 0; q < 4; ++q) {
                f4 v = p[q * 64 + lane];
                f4 w = e[q * 64 + lane];
                s2 += (v[0]*v[0] + v[1]*v[1]) + (v[2]*v[2] + v[3]*v[3]);
                su += (v[0]*w[0] + v[1]*w[1]) + (v[2]*w[2] + v[3]*w[3]);
            }
#pragma unroll
            for (int sh = 32; sh; sh >>= 1) {
                s2 += __shfl_xor(s2, sh, 64);
                su += __shfl_xor(su, sh, 64);
            }
            if (lane == 0) bias2[c] = s2 - 2.f * su;
        }
    }
}

// P1raw [2048][128] fp32 -> wv [128][2048] bf16 hi/lo (coalesced)
__global__ __launch_bounds__(256)
void tposeP1(const float* __restrict__ p1, short* __restrict__ hi,
             short* __restrict__ lo)
{
    tpose64(p1, hi, lo, 2048, 128, blockIdx.x, threadIdx.x);
}

// ============================================================
// gemm256: 256x256-tile 8-wave plain-bf16 implicit-GEMM conv with
// counted-vmcnt deep pipeline (A and B both via global_load_lds). [R8 form]
// ============================================================
template<int EPI>
__global__ __launch_bounds__(512, 2)
void gemm256(const short* __restrict__ aSrc, const short* __restrict__ wHi,
             const float* __restrict__ bias, const float* __restrict__ gamma,
             const float* __restrict__ beta, void* __restrict__ oHi,
             double* __restrict__ sacc, const short* __restrict__ zsrc,
             int IH, int IW, int OHOW, int OW, int N, int K, int off,
             int ntShift, float bns)
{
    extern __shared__ short smem[];

    const int tid = threadIdx.x;
    const int w = tid >> 6;
    const int l = tid & 63;
    const int lr = l >> 3;
    const int lc = l & 7;
    const int fr = l & 15, fq = l >> 4;
    const int wm = (w >> 2) * 128;
    const int wn = (w & 3) * 64;

    int m0, n0;
    {
        const int nwg = gridDim.x;
        const int bid = blockIdx.x;
        const int q = nwg >> 3, r = nwg & 7;
        const int xcd = bid & 7, c = bid >> 3;
        const int wg = (xcd < r ? xcd * (q + 1) : r * (q + 1) + (xcd - r) * q) + c;
        const int NTm1 = (1 << ntShift) - 1;
        m0 = (wg >> ntShift) * 256;
        n0 = (wg & NTm1) * 256;
    }

    int bOff[4], oiA[4], ojA[4], bRowB[4];
#pragma unroll
    for (int i = 0; i < 4; ++i) {
        int row = (w << 5) + (i << 3) + lr;
        int m = m0 + row;
        int b = m / OHOW; int rem = m - b * OHOW;
        oiA[i] = rem / OW; ojA[i] = rem - oiA[i] * OW;
        bOff[i] = b * IH * IW;
        bRowB[i] = (n0 + row) * K;
    }
    const int swz = (lc ^ lr) << 3;

    auto stage = [&](int sel, int kc) {
        short* Ab = smem + sel * 16384;
        short* Bb = smem + 32768 + sel * 16384;
        const int t = kc >> 9;
        const int ci = (kc & 511) + swz;
        const int di = (t >> 1) + off, dj = (t & 1) + off;
#pragma unroll
        for (int i = 0; i < 4; ++i) {
            int ii = oiA[i] + di, jj = ojA[i] + dj;
            bool v = (ii >= 0) && (ii < IH) && (jj >= 0) && (jj < IW);
            const short* sA = v ? aSrc + (long)(bOff[i] + ii * IW + jj) * 512 + ci
                                : zsrc + (l << 3);
            __builtin_amdgcn_global_load_lds(
                (const __attribute__((address_space(1))) void*)sA,
                (__attribute__((address_space(3))) void*)(Ab + (((w << 5) + (i << 3)) * 64)),
                16, 0, 0);
            const short* sB = wHi + bRowB[i] + kc + swz;
            __builtin_amdgcn_global_load_lds(
                (const __attribute__((address_space(1))) void*)sB,
                (__attribute__((address_space(3))) void*)(Bb + (((w << 5) + (i << 3)) * 64)),
                16, 0, 0);
        }
    };

    f4 acc[8][4];
#pragma unroll
    for (int a = 0; a < 8; ++a)
#pragma unroll
        for (int b = 0; b < 4; ++b) acc[a][b] = (f4){0.f, 0.f, 0.f, 0.f};

    const int NT = K >> 6;
    stage(0, 0);
    stage(1, 64);

    for (int t = 0; t < NT; ++t) {
        const int sel = t & 1;
        const short* Ab = smem + sel * 16384;
        const short* Bb = smem + 32768 + sel * 16384;

        if (t < NT - 1) asm volatile("s_waitcnt vmcnt(8)" ::: "memory");
        else            asm volatile("s_waitcnt vmcnt(0)" ::: "memory");
        __builtin_amdgcn_s_barrier();
        __builtin_amdgcn_sched_barrier(0);

        s8 af[8], bf[4];
#pragma unroll
        for (int mf = 0; mf < 8; ++mf) {
            int row = wm + mf * 16 + fr;
            int c = fq ^ (row & 7);
            af[mf] = *(const s8*)&Ab[row * 64 + (c << 3)];
        }
#pragma unroll
        for (int nf = 0; nf < 4; ++nf) {
            int row = wn + nf * 16 + fr;
            int c = fq ^ (row & 7);
            bf[nf] = *(const s8*)&Bb[row * 64 + (c << 3)];
        }
        asm volatile("s_waitcnt lgkmcnt(0)" ::: "memory");
        __builtin_amdgcn_sched_barrier(0);
        __builtin_amdgcn_s_setprio(1);
#pragma unroll
        for (int mf = 0; mf < 8; ++mf)
#pragma unroll
            for (int nf = 0; nf < 4; ++nf)
                acc[mf][nf] = __builtin_amdgcn_mfma_f32_16x16x32_bf16(
                    af[mf], bf[nf], acc[mf][nf], 0, 0, 0);
        __builtin_amdgcn_s_setprio(0);

#pragma unroll
        for (int mf = 0; mf < 8; ++mf) {
            int row = wm + mf * 16 + fr;
            int c = (4 + fq) ^ (row & 7);
            af[mf] = *(const s8*)&Ab[row * 64 + (c << 3)];
        }
#pragma unroll
        for (int nf = 0; nf < 4; ++nf) {
            int row = wn + nf * 16 + fr;
            int c = (4 + fq) ^ (row & 7);
            bf[nf] = *(const s8*)&Bb[row * 64 + (c << 3)];
        }
        asm volatile("s_waitcnt lgkmcnt(0)" ::: "memory");
        __builtin_amdgcn_sched_barrier(0);
        __builtin_amdgcn_s_barrier();
        __builtin_amdgcn_sched_barrier(0);
        if (t + 2 < NT) stage(sel, (t + 2) << 6);

        __builtin_amdgcn_s_setprio(1);
#pragma unroll
        for (int mf = 0; mf < 8; ++mf)
#pragma unroll
            for (int nf = 0; nf < 4; ++nf)
                acc[mf][nf] = __builtin_amdgcn_mfma_f32_16x16x32_bf16(
                    af[mf], bf[nf], acc[mf][nf], 0, 0, 0);
        __builtin_amdgcn_s_setprio(0);
    }

    if (EPI == 3) {
        float bi[4];
#pragma unroll
        for (int nf = 0; nf < 4; ++nf) bi[nf] = bias[n0 + wn + nf * 16 + fr];
        double tsum = 0.0;
#pragma unroll
        for (int mf = 0; mf < 8; ++mf)
#pragma unroll
            for (int j = 0; j < 4; ++j) {
                long gm = m0 + wm + mf * 16 + fq * 4 + j;
                float* orow = (float*)oHi + gm * (long)N + n0;
#pragma unroll
                for (int nf = 0; nf < 4; ++nf) {
                    float v = acc[mf][nf][j] + bi[nf];
                    orow[wn + nf * 16 + fr] = v;
                    tsum += (double)v * v;
                }
            }
        __syncthreads();
        double* rd = (double*)smem;
        rd[tid] = tsum; __syncthreads();
        for (int h = 256; h; h >>= 1) {
            if (tid < h) rd[tid] += rd[tid + h];
            __syncthreads();
        }
        if (tid == 0) atomicAdd(sacc, rd[0]);
    } else {
        float bi[4], ga[4], be[4];
#pragma unroll
        for (int nf = 0; nf < 4; ++nf) {
            int col = n0 + wn + nf * 16 + fr;
            bi[nf] = bias[col]; ga[nf] = gamma[col]; be[nf] = beta[col];
        }
#pragma unroll
        for (int mf = 0; mf < 8; ++mf)
#pragma unroll
            for (int j = 0; j < 4; ++j) {
                long gm = m0 + wm + mf * 16 + fq * 4 + j;
                short* orow = (short*)oHi + gm * (long)N + n0;
#pragma unroll
                for (int nf = 0; nf < 4; ++nf) {
                    float v = ga[nf] * ((acc[mf][nf][j] + bi[nf]) * bns) + be[nf];
                    orow[wn + nf * 16 + fr] = (short)bfr(fmaxf(v, 0.f));
                }
            }
    }
}

// ============================================================
// 128^2 template (proven) for split kernels, folds, VQ, and D3.
// EPI==2 now also gathers o_q rows (xref = cb fp32, oHi = o_q).
// ============================================================
template<int SPLIT, int ASRC, int EPI, int OUTF>
__global__ __launch_bounds__(256, 2)
void mfma_conv(const void* __restrict__ aHi, const void* __restrict__ aLo,
               const short* __restrict__ wHi, const short* __restrict__ wLo,
               const float* __restrict__ bias, const float* __restrict__ gamma,
               const float* __restrict__ beta,
               void* __restrict__ oHi, void* __restrict__ oLo,
               int* __restrict__ idxo,
               const float* __restrict__ xref, float* __restrict__ colsum,
               double* __restrict__ sacc,
               int IH, int IW, int Cin, int cinShift, int OHOW, int OW,
               int N, int K, int off, int ntShift, float bns)
{
    constexpr int PL = 128 * 64;
    constexpr int NPL = (SPLIT == 1) ? 3 : 4;
    __shared__ short smem[NPL * PL];
    short* Ah = smem;
    short* Al  = smem + PL;
    short* BhS = smem + 2 * PL;
    short* BlS = smem + 3 * PL;

    const int tid = threadIdx.x;
    const int lane = tid & 63, wid = tid >> 6;
    const int fr = lane & 15, fq = lane >> 4;
    const int wm = (wid >> 1) * 64, wn = (wid & 1) * 64;

    int m0, n0;
    {
        const int nwg = gridDim.x;
        const int bid = blockIdx.x;
        const int q = nwg >> 3, r = nwg & 7;
        const int xcd = bid & 7, c = bid >> 3;
        const int wg = (xcd < r ? xcd * (q + 1) : r * (q + 1) + (xcd - r) * q) + c;
        const int NTm1 = (1 << ntShift) - 1;
        m0 = (wg >> ntShift) * 128;
        n0 = (wg & NTm1) * 128;
    }

    const int sr = tid >> 1;
    const int skh = (tid & 1) << 5;

    long tapOff[4]; bool tv[4];
    {
        int m = m0 + sr;
        int b = m / OHOW; int rem = m - b * OHOW;
        int oi = rem / OW; int oj = rem - oi * OW;
#pragma unroll
        for (int t = 0; t < 4; ++t) {
            int ii = oi + (t >> 1) + off, jj = oj + (t & 1) + off;
            bool v = (ii >= 0) && (ii < IH) && (jj >= 0) && (jj < IW);
            tv[t] = v;
            tapOff[t] = ((long)b * IH + (v ? ii : 0)) * IW + (v ? jj : 0);
        }
    }

    f4 acc[4][4];
#pragma unroll
    for (int a = 0; a < 4; ++a)
#pragma unroll
        for (int b = 0; b < 4; ++b) acc[a][b] = (f4){0.f, 0.f, 0.f, 0.f};

    const short* wHrow = wHi + (long)(n0 + sr) * K;
    const short* wLrow = (SPLIT == 2) ? (wLo + (long)(n0 + sr) * K) : nullptr;

    const int swzW = (sr & 7) << 3;
    const int sbase = sr * 64;

    s8 rah[4], ral[4], rbh[4], rbl[4];
    f4 rax0[4], rax1[4];

    auto LOADREGS = [&](int kc) {
        const int kk = kc + skh;
        const int t = kk >> cinShift;
        const int ci = kk & (Cin - 1);
        const bool v = tv[t];
        if (ASRC == 0) {
            const float* p = (const float*)aHi + tapOff[t] * Cin + ci;
#pragma unroll
            for (int q = 0; q < 4; ++q) {
                rax0[q] = v ? ldg4(p + 8 * q) : (f4){0.f,0.f,0.f,0.f};
                rax1[q] = v ? ldg4(p + 8 * q + 4) : (f4){0.f,0.f,0.f,0.f};
            }
        } else if (ASRC == 1) {
            const short* ph = (const short*)aHi + tapOff[t] * Cin + ci;
            const short* pl = (const short*)aLo + tapOff[t] * Cin + ci;
#pragma unroll
            for (int q = 0; q < 4; ++q) {
                rah[q] = v ? *(const s8*)(ph + 8 * q) : z8();
                ral[q] = v ? *(const s8*)(pl + 8 * q) : z8();
            }
        } else {
            const short* ph = (const short*)aHi + tapOff[t] * Cin + ci;
#pragma unroll
            for (int q = 0; q < 4; ++q) rah[q] = v ? *(const s8*)(ph + 8 * q) : z8();
        }
        if (SPLIT == 2) {
#pragma unroll
            for (int q = 0; q < 4; ++q) {
                rbh[q] = *(const s8*)(wHrow + kc + skh + 8 * q);
                rbl[q] = *(const s8*)(wLrow + kc + skh + 8 * q);
            }
        }
    };

    auto STORE = [&]() {
        if (ASRC == 0) {
#pragma unroll
            for (int q = 0; q < 4; ++q) split8(rax0[q], rax1[q], rah[q], ral[q]);
        }
#pragma unroll
        for (int q = 0; q < 4; ++q) {
            int kx = (skh + 8 * q) ^ swzW;
            *(s8*)&Ah[sbase + kx] = rah[q];
            if (SPLIT == 2) {
                *(s8*)&Al[sbase + kx]  = ral[q];
                *(s8*)&BhS[sbase + kx] = rbh[q];
                *(s8*)&BlS[sbase + kx] = rbl[q];
            }
        }
    };

    auto stageB = [&](int bsel, int kc2) {
        short* bb = smem + (1 + bsel) * PL;
        const int rr0 = wid << 5;
#pragma unroll
        for (int i = 0; i < 4; ++i) {
            const int r = rr0 + 8 * i + (lane >> 3);
            const int c = lane & 7;
            const short* src = wHi + (long)(n0 + r) * K + kc2 + 8 * (c ^ (r & 7));
            __builtin_amdgcn_global_load_lds(
                (const __attribute__((address_space(1))) void*)src,
                (__attribute__((address_space(3))) void*)(bb + (rr0 + 8 * i) * 64),
                16, 0, 0);
        }
    };

    int bcur = 0;
    LOADREGS(0);
    if (SPLIT == 1) stageB(0, 0);

    for (int kc = 0; kc < K; kc += 64) {
        if (SPLIT == 1) {
            asm volatile("s_waitcnt lgkmcnt(0)" ::: "memory");
            __builtin_amdgcn_s_barrier();
            STORE();
            if (kc + 64 < K) {
                stageB(bcur ^ 1, kc + 64);
                asm volatile("s_waitcnt vmcnt(4)" ::: "memory");
            } else {
                asm volatile("s_waitcnt vmcnt(0)" ::: "memory");
            }
            __builtin_amdgcn_sched_barrier(0);
            asm volatile("s_waitcnt lgkmcnt(0)" ::: "memory");
            __builtin_amdgcn_s_barrier();
        } else {
            __syncthreads();
            STORE();
            __syncthreads();
        }
        if (kc + 64 < K) LOADREGS(kc + 64);

        const short* Bc = (SPLIT == 1) ? (smem + (1 + bcur) * PL) : BhS;

        __builtin_amdgcn_s_setprio(1);
#pragma unroll
        for (int ks = 0; ks < 2; ++ks) {
            const int colk = ks * 32 + fq * 8;
            s8 afh[4], afl[4], bfh[4], bfl[4];
#pragma unroll
            for (int mf = 0; mf < 4; ++mf) {
                int ar = wm + mf * 16 + fr;
                int ai = ar * 64 + (colk ^ ((ar & 7) << 3));
                afh[mf] = *(const s8*)&Ah[ai];
                if (SPLIT == 2) afl[mf] = *(const s8*)&Al[ai];
            }
#pragma unroll
            for (int nf = 0; nf < 4; ++nf) {
                int br = wn + nf * 16 + fr;
                int bi2 = br * 64 + (colk ^ ((br & 7) << 3));
                bfh[nf] = *(const s8*)&Bc[bi2];
                if (SPLIT == 2) bfl[nf] = *(const s8*)&BlS[bi2];
            }
#pragma unroll
            for (int mf = 0; mf < 4; ++mf)
#pragma unroll
                for (int nf = 0; nf < 4; ++nf) {
                    acc[mf][nf] = __builtin_amdgcn_mfma_f32_16x16x32_bf16(
                        afh[mf], bfh[nf], acc[mf][nf], 0, 0, 0);
                    if (SPLIT == 2) {
                        acc[mf][nf] = __builtin_amdgcn_mfma_f32_16x16x32_bf16(
                            afh[mf], bfl[nf], acc[mf][nf], 0, 0, 0);
                        acc[mf][nf] = __builtin_amdgcn_mfma_f32_16x16x32_bf16(
                            afl[mf], bfh[nf], acc[mf][nf], 0, 0, 0);
                    }
                }
        }
        __builtin_amdgcn_s_setprio(0);
        bcur ^= 1;
    }

    if (EPI == 2) {
        // dist (mod row-const) = bias[col] - 2*acc ; argmin over 128 cols;
        // winner-dist sum -> sacc; fused o_q gather (xref = cb, oHi = o_q).
        __syncthreads();
        float* pbv = (float*)smem;                    // [2][128] floats
        int*   piv = (int*)((float*)smem + 256);      // [2][128] ints
        int*   fidx = (int*)((float*)smem + 512);     // [128] final idx
        double* rd = (double*)((float*)smem + 768);   // [256] doubles
        float cnv[4];
#pragma unroll
        for (int nf = 0; nf < 4; ++nf) cnv[nf] = bias[n0 + wn + nf * 16 + fr];
#pragma unroll
        for (int mf = 0; mf < 4; ++mf)
#pragma unroll
            for (int j = 0; j < 4; ++j) {
                float best = 3.4e38f; int bi = 0;
#pragma unroll
                for (int nf = 0; nf < 4; ++nf) {
                    float d = cnv[nf] - 2.0f * acc[mf][nf][j];
                    int col = wn + nf * 16 + fr;
                    if (d < best) { best = d; bi = col; }
                }
#pragma unroll
                for (int sh = 1; sh <= 8; sh <<= 1) {
                    float ov = __shfl_xor(best, sh, 64);
                    int ob = __shfl_xor(bi, sh, 64);
                    if (ov < best || (ov == best && ob < bi)) { best = ov; bi = ob; }
                }
                if (fr == 0) {
                    int r = wm + mf * 16 + fq * 4 + j;
                    pbv[(wid & 1) * 128 + r] = best;
                    piv[(wid & 1) * 128 + r] = bi;
                }
            }
        __syncthreads();
        double win = 0.0;
        if (tid < 128) {
            float b0 = pbv[tid], b1 = pbv[128 + tid];
            int i0 = piv[tid], i1 = piv[128 + tid];
            int sel = (b1 < b0) ? i1 : i0;
            idxo[m0 + tid] = sel;
            fidx[tid] = sel;
            win = (double)((b1 < b0) ? b1 : b0);
        }
        __syncthreads();
        rd[tid] = win; __syncthreads();
        for (int h = 128; h; h >>= 1) {
            if (tid < h) rd[tid] += rd[tid + h];
            __syncthreads();
        }
        if (tid == 0) atomicAdd(sacc, rd[0]);
        // ---- fused gather: o_q[m0+r] = cb[fidx[r]] ----
        const float* cbf = xref;
        float* oq = (float*)oHi;
#pragma unroll 4
        for (int r = 0; r < 128; ++r) {
            int c = fidx[r];
            f4 v = *(const f4*)&cbf[(long)c * 1024 + 4 * tid];
            *(f4*)&oq[((long)(m0 + r)) * 1024 + 4 * tid] = v;
        }
        return;
    }

    float bi[4], ga[4], be[4];
#pragma unroll
    for (int nf = 0; nf < 4; ++nf) {
        int col = n0 + wn + nf * 16 + fr;
        bi[nf] = bias[col];
        if (EPI == 1) { ga[nf] = gamma[col]; be[nf] = beta[col]; }
    }
    double tsum = 0.0;
    float csum[4] = {0.f, 0.f, 0.f, 0.f};
#pragma unroll
    for (int mf = 0; mf < 4; ++mf)
#pragma unroll
        for (int j = 0; j < 4; ++j) {
            long gm = m0 + wm + mf * 16 + fq * 4 + j;
#pragma unroll
            for (int nf = 0; nf < 4; ++nf) {
                int col = n0 + wn + nf * 16 + fr;
                float vv = acc[mf][nf][j] + bi[nf];
                if (EPI == 1) {
                    vv = ga[nf] * (vv * bns) + be[nf];
                    vv = fmaxf(vv, 0.f);
                }
                long o = gm * (long)N + col;
                if (OUTF == 0) {
                    ((float*)oHi)[o] = vv;
                } else if (OUTF == 2) {
                    ((short*)oHi)[o] = (short)bfr(vv);
                } else {
                    unsigned short h = bfr(vv);
                    ((short*)oHi)[o] = (short)h;
                    ((short*)oLo)[o] = (short)bfr(vv - bff(h));
                }
                if (EPI == 3) tsum += (double)vv * vv;
                if (EPI == 4) {
                    float d = vv - xref[o];
                    tsum += (double)d * d;
                    csum[nf] += vv;
                }
            }
        }
    if (EPI == 4) {
        int bb128 = (m0 >> 8) * 128;
#pragma unroll
        for (int nf = 0; nf < 4; ++nf)
            atomicAdd(&colsum[bb128 + n0 + wn + nf * 16 + fr], csum[nf]);
    }
    if (EPI == 3 || EPI == 4) {
        __syncthreads();
        double* rd = (double*)smem;
        rd[tid] = tsum; __syncthreads();
        for (int h = 128; h; h >>= 1) {
            if (tid < h) rd[tid] += rd[tid + h];
            __syncthreads();
        }
        if (tid == 0) atomicAdd(sacc, rd[0]);
    }
}

// D1 via folded codebook table
__global__ __launch_bounds__(256)
void d1_gather(const float* __restrict__ CD, const int* __restrict__ idx,
               const float* __restrict__ db1, const float* __restrict__ dg1,
               const float* __restrict__ dbt1, short* __restrict__ out, float bns)
{
    int m = blockIdx.x * 4 + (threadIdx.x >> 6);
    int lane = threadIdx.x & 63;
    if (m >= 50176) return;
    int b = m / 196, rem = m - b * 196;
    int oi = rem / 14, oj = rem - oi * 14;
    float2 acc[4];
#pragma unroll
    for (int q = 0; q < 4; ++q) acc[q] = make_float2(0.f, 0.f);
#pragma unroll
    for (int t = 0; t < 4; ++t) {
        int ii = oi - 1 + (t >> 1), jj = oj - 1 + (t & 1);
        if (ii >= 0 && ii < 13 && jj >= 0 && jj < 13) {
            int c = idx[(b * 13 + ii) * 13 + jj];
            const float2* p = (const float2*)(CD + ((long)c * 2048 + t * 512));
#pragma unroll
            for (int q = 0; q < 4; ++q) {
                float2 v = p[lane + 64 * q];
                acc[q].x += v.x; acc[q].y += v.y;
            }
        }
    }
#pragma unroll
    for (int q = 0; q < 4; ++q) {
        int n = 2 * (lane + 64 * q);
        float v0 = fmaxf(dg1[n]     * ((acc[q].x + db1[n])     * bns) + dbt1[n],     0.f);
        float v1 = fmaxf(dg1[n + 1] * ((acc[q].y + db1[n + 1]) * bns) + dbt1[n + 1], 0.f);
        short2 s2v;
        s2v.x = (short)bfr(v0); s2v.y = (short)bfr(v1);
        ((short2*)out)[(long)m * 256 + lane + 64 * q] = s2v;
    }
}

// vq_mean + loss finalize (block 0 thread 0 writes loss)
__global__ void vq_mean_fin(const float* __restrict__ colsum,
                            const float* __restrict__ mask,
                            const double* __restrict__ s,
                            float* __restrict__ o, float* __restrict__ loss)
{
    __shared__ float red[128];
    int b = blockIdx.x;
    int d = threadIdx.x;
    red[d] = mask[b * 256 + d] + mask[b * 256 + 128 + d];
    __syncthreads();
    for (int h = 64; h; h >>= 1) { if (d < h) red[d] += red[d + h]; __syncthreads(); }
    o[b * 128 + d] = colsum[b * 128 + d] / red[0];
    if (b == 0 && d == 0)
        loss[0] = (float)(s[0] / 8388608.0 + 1.25 * ((s[1] + s[2]) / 44302336.0));
}

extern "C" void kernel_launch(void* const* d_in, const int* in_sizes, int n_in,
                              void* d_out, int out_size, void* d_ws, size_t ws_size,
                              hipStream_t stream)
{
    const float* x    = (const float*)d_in[0];
    const float* mask = (const float*)d_in[1];
    const float* cb   = (const float*)d_in[2];
    const float* ew1 = (const float*)d_in[3];
    const float* eb1 = (const float*)d_in[4];
    const float* eg1 = (const float*)d_in[5];
    const float* ebt1= (const float*)d_in[6];
    const float* ew2 = (const float*)d_in[7];
    const float* eb2 = (const float*)d_in[8];
    const float* eg2 = (const float*)d_in[9];
    const float* ebt2= (const float*)d_in[10];
    const float* ew3 = (const float*)d_in[11];
    const float* eb3 = (const float*)d_in[12];
    const float* dw1 = (const float*)d_in[13];
    const float* db1 = (const float*)d_in[14];
    const float* dg1 = (const float*)d_in[15];
    const float* dbt1= (const float*)d_in[16];
    const float* dw2 = (const float*)d_in[17];
    const float* db2 = (const float*)d_in[18];
    const float* dg2 = (const float*)d_in[19];
    const float* dbt2= (const float*)d_in[20];
    const float* dw3 = (const float*)d_in[21];
    const float* db3 = (const float*)d_in[22];

    float* out = (float*)d_out;
    float* o_vqmean = out;
    float* o_vqx    = out + 32768;
    float* o_xe     = out + 8421376;
    float* o_q      = out + 52723712;
    float* o_loss   = out + 97026048;

    float* base;
    if (ws_size >= (size_t)WS_FLOATS * 4) {
        base = (float*)d_ws;
    } else {
        void* p = nullptr;
        hipGetSymbolAddress(&p, HIP_SYMBOL(g_fallback));
        base = (float*)p;
    }

    float* cur = base;
    short* h1h = (short*)cur; cur += 7372800;
    short* h1l = (short*)cur; cur += 7372800;
    short* h2h = (short*)cur; cur += 12845056;
    short* h2l = (short*)cur; cur += 12845056;
    short* d1o = (short*)cur; cur += 12845056;
    short* d2o = (short*)cur; cur += 7372800;
    short* ewt1h = (short*)cur; cur += 65536;
    short* ewt1l = (short*)cur; cur += 65536;
    short* ewt2h = (short*)cur; cur += 262144;
    short* ewt2l = (short*)cur; cur += 262144;
    short* ewt3h = (short*)cur; cur += 1048576;
    short* dwt1Th = (short*)cur; cur += 1048576;
    short* dwt1Tl = (short*)cur; cur += 1048576;
    short* dwt2h = (short*)cur; cur += 262144;
    short* dwt3h = (short*)cur; cur += 65536;
    short* cbh   = (short*)cur; cur += 65536;
    short* cbl   = (short*)cur; cur += 65536;
    float* P1raw = cur; cur += 262144;
    short* wvh   = (short*)cur; cur += 131072;
    short* wvl   = (short*)cur; cur += 131072;
    float* CDt   = cur; cur += 262144;
    float* bias2 = cur; cur += 128;
    float* zbuf  = cur; cur += 2048;
    int* idxb = (int*)cur; cur += 43264;
    float* colsum = cur; cur += 32768;
    double* sdbl = (double*)cur; cur += 16;   // [0]=recon [1]=fn [2]=best

    const float bns = (float)(1.0 / sqrt(1.0 + 1e-3));

    // dynamic-LDS opt-ins
    hipFuncSetAttribute(reinterpret_cast<const void*>(&gemm256<3>),
                        hipFuncAttributeMaxDynamicSharedMemorySize, 131072);
    hipFuncSetAttribute(reinterpret_cast<const void*>(&gemm256<1>),
                        hipFuncAttributeMaxDynamicSharedMemorySize, 131072);

    // ---- zero accumulators + prep (transposes + codebook + code_bias) ----
    hipMemsetAsync(colsum, 0, 32768 * sizeof(float), stream);
    hipMemsetAsync(sdbl, 0, 3 * sizeof(double), stream);
    tpose_all<<<1889, 256, 0, stream>>>(ew1, ew2, ew3, dw1, dw2, dw3, cb, eb3,
        ewt1h, ewt1l, ewt2h, ewt2l, ewt3h, dwt1Th, dwt1Tl, dwt2h, dwt3h,
        cbh, cbl, zbuf, bias2);

    // ---- folds ----
    mfma_conv<2, 0, 0, 0><<<16, 256, 0, stream>>>(
        ew3, nullptr, cbh, cbl, zbuf, nullptr, nullptr, P1raw, nullptr, nullptr,
        nullptr, nullptr, nullptr,
        2, 2050, 1024, 10, 2048, 2048, 128, 1024, 0, 0, bns);
    tposeP1<<<64, 256, 0, stream>>>(P1raw, wvh, wvl);
    mfma_conv<2, 0, 0, 0><<<16, 256, 0, stream>>>(
        cb, nullptr, dwt1Th, dwt1Tl, zbuf, nullptr, nullptr, CDt, nullptr, nullptr,
        nullptr, nullptr, nullptr,
        2, 130, 1024, 10, 128, 128, 2048, 1024, 0, 4, bns);

    // ---- encoder ----
    mfma_conv<2, 0, 1, 1><<<900, 256, 0, stream>>>(
        x, nullptr, ewt1h, ewt1l, eb1, eg1, ebt1, h1h, h1l, nullptr,
        nullptr, nullptr, nullptr,
        16, 16, 128, 7, 225, 15, 256, 512, 0, 1, bns);
    mfma_conv<2, 1, 1, 1><<<1568, 256, 0, stream>>>(
        h1h, h1l, ewt2h, ewt2l, eb2, eg2, ebt2, h2h, h2l, nullptr,
        nullptr, nullptr, nullptr,
        15, 15, 256, 8, 196, 14, 512, 1024, 0, 2, bns);
    // E3: 256^2 deep-pipelined (x_encode fp32 out + fn-sum)
    gemm256<3><<<676, 512, 131072, stream>>>(
        h2h, ewt3h, eb3, nullptr, nullptr, o_xe, sdbl + 1, (const short*)zbuf,
        14, 14, 169, 13, 1024, 2048, 0, 2, bns);

    // ---- VQ: folded dist + argmin + best-sum + fused o_q gather ----
    mfma_conv<2, 1, 2, 0><<<338, 256, 0, stream>>>(
        h2h, h2l, wvh, wvl, bias2, nullptr, nullptr, o_q, nullptr, idxb,
        cb, nullptr, sdbl + 2,
        14, 14, 512, 9, 169, 13, 128, 2048, 0, 0, bns);

    // ---- decoder ----
    d1_gather<<<12544, 256, 0, stream>>>(CDt, idxb, db1, dg1, dbt1, d1o, bns);
    // D2: 256^2 deep-pipelined (bn-relu bf16 out)
    gemm256<1><<<225, 512, 131072, stream>>>(
        d1o, dwt2h, db2, dg2, dbt2, d2o, nullptr, (const short*)zbuf,
        14, 14, 225, 15, 256, 2048, -1, 0, bns);
    // D3: vq_x + recon-sum + colsum fused (128^2 template)
    mfma_conv<1, 2, 4, 0><<<512, 256, 0, stream>>>(
        d2o, nullptr, dwt3h, nullptr, db3, nullptr, nullptr, o_vqx, nullptr, nullptr,
        x, colsum, sdbl + 0,
        15, 15, 256, 8, 256, 16, 128, 1024, -1, 0, bns);

    // ---- outputs (vq_mean + loss in one launch) ----
    vq_mean_fin<<<256, 128, 0, stream>>>(colsum, mask, sdbl, o_vqmean, o_loss);
}